// Round 8
// baseline (191.514 us; speedup 1.0000x reference)
//
#include <hip/hip_runtime.h>
#include <stdint.h>

#define DI __device__ __forceinline__

typedef __attribute__((ext_vector_type(8))) __bf16 bf16x8;
typedef __attribute__((ext_vector_type(8))) unsigned short u16x8;
typedef __attribute__((ext_vector_type(4))) float f32x4;
typedef __attribute__((ext_vector_type(4))) uint32_t u32x4;
typedef unsigned short u16;

constexpr int Bb = 4, Cc = 256, Ss = 4096, HD = 64;
constexpr int ELEMS = Bb * Cc * Ss;  // 4194304

DI float bf2f(u16 h) { union { unsigned u; float f; } x; x.u = ((unsigned)h) << 16; return x.f; }
DI u16 f2bf(float f) {
  union { float f; unsigned u; } x; x.f = f;
  return (u16)((x.u + 0x7FFFu + ((x.u >> 16) & 1u)) >> 16);
}
DI uint32_t pack2bf_trunc(float a, float b) {  // low16=bf(a), high16=bf(b), truncating
  union { float f; uint32_t u; } xa, xb;
  xa.f = a; xb.f = b;
  return __builtin_amdgcn_perm(xb.u, xa.u, 0x07060302u);
}
DI bf16x8 ldfrag(const u16* p) { return __builtin_bit_cast(bf16x8, *(const u16x8*)p); }

// async global->LDS DMA, 16B per lane. LDS dest = wave-uniform base + lane*16 (linear);
// source address is per-lane (carries the swizzle).
DI void g2l16(const u16* g, u16* l) {
  __builtin_amdgcn_global_load_lds((const __attribute__((address_space(1))) uint32_t*)(const void*)g,
                                   (__attribute__((address_space(3))) uint32_t*)(void*)l, 16, 0, 0);
}

// ---------------- kernel 0: x (B,C,S) fp32 -> xt (B,S,C) bf16; + weight conversion fused ----------------
__global__ __launch_bounds__(256) void k_transpose(const float* __restrict__ x, u16* __restrict__ xt,
                                                   const float* __restrict__ wq, const float* __restrict__ wo,
                                                   u16* __restrict__ wqb, u16* __restrict__ wob) {
  __shared__ u16 T[64][72];
  const int st = blockIdx.x, ct = blockIdx.y, b = blockIdx.z;
  const int tid = threadIdx.x;
  // fused weight conversion: 1024 blocks x 256 threads == 262144 == 196608 + 65536
  {
    int flat = blockIdx.x + 64 * blockIdx.y + 256 * blockIdx.z;
    int widx = flat * 256 + tid;
    if (widx < 196608) wqb[widx] = f2bf(wq[widx]);
    else wob[widx - 196608] = f2bf(wo[widx - 196608]);
  }
#pragma unroll
  for (int e = 0; e < 2; e++) {
    int ss = tid + e * 256;
    int r = ss >> 3, seg = ss & 7;
    size_t base = ((size_t)(b * Cc + ct * 64 + r) << 12) + st * 64 + seg * 8;
    const float4* xv = (const float4*)(x + base);
    float4 v0 = xv[0], v1 = xv[1];
    u16x8 t;
    t[0] = f2bf(v0.x); t[1] = f2bf(v0.y); t[2] = f2bf(v0.z); t[3] = f2bf(v0.w);
    t[4] = f2bf(v1.x); t[5] = f2bf(v1.y); t[6] = f2bf(v1.z); t[7] = f2bf(v1.w);
    *(u16x8*)&T[r][(seg ^ ((r >> 3) & 7)) * 8] = t;
  }
  __syncthreads();
#pragma unroll
  for (int e = 0; e < 2; e++) {
    int ss = tid + e * 256;
    int sr = ss >> 3, cseg = ss & 7;
    u16x8 o;
#pragma unroll
    for (int j = 0; j < 8; j++) {
      int row = cseg * 8 + j;
      o[j] = T[row][(((sr >> 3) ^ cseg) * 8) + (sr & 7)];
    }
    *(u16x8*)(xt + ((size_t)(b * Ss + st * 64 + sr) << 8) + ct * 64 + cseg * 8) = o;
  }
}

// ---- shared GEMM staging: rows [r0,r0+128) x cols [k0,k0+32), pitch-40 LDS ----
DI void stage_tile(const u16* __restrict__ src, int pitch, int r0, int k0, u16 (*dst)[40], int tid) {
#pragma unroll
  for (int e = 0; e < 2; e++) {
    int c = tid + e * 256;
    int row = c >> 2, seg = c & 3;
    u16x8 t = *(const u16x8*)(src + (size_t)(r0 + row) * pitch + k0 + seg * 8);
    *(u16x8*)&dst[row][seg * 8] = t;
  }
}

// ---------------- kernel 1: qkv GEMM + fused output layouts ----------------
// q:[bh][s][64]*(0.125*log2e)  k:[bh][s][64]  v -> vt [bh][d][chunk*64+slot] directly.
// ALL epilogues route through the LDS tile for vectorized u16x8 stores (the old q/k path
// did 64 scalar 2B stores/thread — 4x 32B scatter per wave-instr, ~50 MB at poor line
// efficiency). part is uniform per block (blockIdx.y).
__global__ __launch_bounds__(256) void k_qkv(const u16* __restrict__ xt, const u16* __restrict__ w,
                                             const float* __restrict__ bias,
                                             u16* __restrict__ q, u16* __restrict__ kk_, u16* __restrict__ vt) {
  __shared__ union {
    u16 ab[2][128][40];   // As, Bs during K-loop
    u16 tile[128][136];   // epilogue staging (pitch 136: 16B-aligned rows, conflict-benign)
  } sm;
  const int tid = threadIdx.x;
  const int wv = tid >> 6, lane = tid & 63;
  const int wm = wv >> 1, wn = wv & 1;
  const int lr = lane & 15, quad = lane >> 4;
  const int r0 = blockIdx.x * 128;
  const int j0 = blockIdx.y * 128;
  f32x4 acc[4][4] = {};
  for (int k0 = 0; k0 < 256; k0 += 32) {
    __syncthreads();
    stage_tile(xt, 256, r0, k0, sm.ab[0], tid);
    stage_tile(w, 256, j0, k0, sm.ab[1], tid);
    __syncthreads();
    bf16x8 a[4], b[4];
#pragma unroll
    for (int mt = 0; mt < 4; mt++) a[mt] = ldfrag(&sm.ab[0][wm * 64 + mt * 16 + lr][quad * 8]);
#pragma unroll
    for (int nt = 0; nt < 4; nt++) b[nt] = ldfrag(&sm.ab[1][wn * 64 + nt * 16 + lr][quad * 8]);
#pragma unroll
    for (int mt = 0; mt < 4; mt++)
#pragma unroll
      for (int nt = 0; nt < 4; nt++)
        acc[mt][nt] = __builtin_amdgcn_mfma_f32_16x16x32_bf16(a[mt], b[nt], acc[mt][nt], 0, 0, 0);
  }
  float bj[4];
#pragma unroll
  for (int nt = 0; nt < 4; nt++) bj[nt] = bias[j0 + wn * 64 + nt * 16 + lr];
  __syncthreads();  // drain last ldfrags before overwriting the union
  if (blockIdx.y < 4) {
    // q/k path: stage (acc+bias)*sc to LDS, then coalesced u16x8 stores
    const int part = blockIdx.y >> 1;  // 0=q, 1=k
    u16* outp = part ? kk_ : q;
    const float sc = part ? 1.0f : 0.18033688f;  // 0.125*log2(e), exp2-domain scores
#pragma unroll
    for (int nt = 0; nt < 4; nt++) {
      int lc = wn * 64 + nt * 16 + lr;
#pragma unroll
      for (int mt = 0; mt < 4; mt++)
#pragma unroll
        for (int rg = 0; rg < 4; rg++)
          sm.tile[wm * 64 + mt * 16 + quad * 4 + rg][lc] = f2bf((acc[mt][nt][rg] + bj[nt]) * sc);
    }
    __syncthreads();
    const int hb2 = (blockIdx.y & 1) * 2;  // head base within part
#pragma unroll
    for (int it = 0; it < 8; it++) {
      int seg = tid + it * 256;            // 2048 u16x8 segments
      int row = seg >> 4, cs = seg & 15;   // consecutive tids -> consecutive cols (coalesced)
      u16x8 o = *(const u16x8*)&sm.tile[row][cs * 8];
      int head = hb2 + (cs >> 3), d0 = (cs & 7) * 8;
      int rr = r0 + row, b_ = rr >> 12, s = rr & 4095;
      *(u16x8*)(outp + ((size_t)((b_ * 4 + head) * Ss + s) << 6) + d0) = o;
    }
  } else {
    // v path: acc tile -> LDS -> transposed+permuted vt write
    const int hb = (blockIdx.y - 4) * 2;  // head base (0 or 2)
#pragma unroll
    for (int nt = 0; nt < 4; nt++) {
      int lc = wn * 64 + nt * 16 + lr;
#pragma unroll
      for (int mt = 0; mt < 4; mt++)
#pragma unroll
        for (int rg = 0; rg < 4; rg++)
          sm.tile[wm * 64 + mt * 16 + quad * 4 + rg][lc] = f2bf(acc[mt][nt][rg] + bj[nt]);
    }
    __syncthreads();
    const int b2 = r0 >> 12, sbase = r0 & 4095;
#pragma unroll
    for (int it = 0; it < 8; it++) {
      int seg = tid + it * 256;        // 2048 u16x8 segments
      int sq = seg & 15, hd = seg >> 4;  // consecutive tids -> consecutive slots (coalesced)
      int c = sq >> 3, s8 = sq & 7;
      u16x8 o;
#pragma unroll
      for (int j = 0; j < 8; j++) {
        int slot = s8 * 8 + j;
        int sw = (((slot >> 5) & 1) << 5) | (((slot >> 2) & 1) << 4) |
                 (((slot >> 3) & 3) << 2) | (slot & 3);  // k_vt's w6 bijection
        o[j] = sm.tile[c * 64 + sw][hd];
      }
      int head = hb + (hd >> 6), d = hd & 63;
      *(u16x8*)(vt + ((size_t)((b2 * 4 + head) * 64 + d) << 12) + sbase + c * 64 + s8 * 8) = o;
    }
  }
}

// ---------------- kernel 2: flash attention, S^T form, exp2 no-max softmax ----------------
// 8-wave (512-thread) blocks of 32-q waves, 256 q-rows/block (r6 structure, best measured).
// nsplit removed: single pass over all 64 kv-chunks, writes normalized AO directly —
// k_oproj's combine (33.5 MB AOP re-read + VALU) disappears. grid (16,16) = 256 blocks.
__global__ __launch_bounds__(512, 4) void k_attn(const u16* __restrict__ Q, const u16* __restrict__ K,
                                                 const u16* __restrict__ VT, u16* __restrict__ AO) {
  __shared__ u16 Kl[2][64][64];
  __shared__ u16 Vl[2][64][64];
  const int tid = threadIdx.x;
  const int wv = tid >> 6, lane = tid & 63;
  const int lr = lane & 15, quad = lane >> 4;
  const int bh = blockIdx.y;
  const int b_ = bh >> 2, head = bh & 3;
  const int qbase = blockIdx.x * 256 + wv * 32;
  const u16* Qh = Q + (size_t)bh * Ss * HD;
  const u16* Kh = K + (size_t)bh * Ss * HD;
  const u16* Vh = VT + (size_t)bh * HD * Ss;  // [d][perm(s)]

  bf16x8 qb[2][2];
#pragma unroll
  for (int nt = 0; nt < 2; nt++)
#pragma unroll
    for (int ks = 0; ks < 2; ks++)
      qb[nt][ks] = ldfrag(Qh + (size_t)(qbase + nt * 16 + lr) * HD + ks * 32 + quad * 8);

  u16x8 ov;
#pragma unroll
  for (int j = 0; j < 8; j++) ov[j] = 0x3F80;
  const bf16x8 ones = __builtin_bit_cast(bf16x8, ov);

  f32x4 O[2][4] = {};
  f32x4 lacc[2] = {};

  // DMA staging: 8 waves cover 64 rows (wave wv: rows wv*8..wv*8+7). Lane l writes LDS
  // granule (row = wv*8 + l>>3, slot = l&7); source granule = (l&7) ^ (row&7) = (l&7)^(l>>3).
  const int srow = wv * 8 + (lane >> 3);
  const int sseg = ((lane & 7) ^ (lane >> 3)) * 8;
  const u16* pK = Kh + ((size_t)srow << 6) + sseg;
  const u16* pV = Vh + ((size_t)srow << 12) + sseg;
  auto stage = [&](int buf) {
    g2l16(pK, &Kl[buf][wv * 8][0]);
    g2l16(pV, &Vl[buf][wv * 8][0]);
    pK += 4096; pV += 64;  // next chunk
  };

  stage(0);
  __syncthreads();

  for (int kc = 0; kc < 64; kc++) {
    const int cur = kc & 1;
    if (kc + 1 < 64) stage(cur ^ 1);  // async into other buffer; drains at loop-end barrier

    u32x4 pa[2][2];  // [kv-half][q-group]: packed bf16 P fragments (PV A-operands)
#pragma unroll
    for (int t = 0; t < 4; t++) {  // 16-row kv tiles
      const int krow = t * 16 + lr;
      bf16x8 ka0 = ldfrag(&Kl[cur][krow][(quad ^ (lr & 7)) * 8]);
      bf16x8 ka1 = ldfrag(&Kl[cur][krow][((4 + quad) ^ (lr & 7)) * 8]);
      f32x4 St[2] = {};
      __builtin_amdgcn_s_setprio(1);
#pragma unroll
      for (int nt = 0; nt < 2; nt++)
        St[nt] = __builtin_amdgcn_mfma_f32_16x16x32_bf16(ka0, qb[nt][0], St[nt], 0, 0, 0);
#pragma unroll
      for (int nt = 0; nt < 2; nt++)
        St[nt] = __builtin_amdgcn_mfma_f32_16x16x32_bf16(ka1, qb[nt][1], St[nt], 0, 0, 0);
      __builtin_amdgcn_s_setprio(0);
      const int h = t >> 1, k2 = (t & 1) * 2;
#pragma unroll
      for (int nt = 0; nt < 2; nt++) {
        float p0 = __builtin_amdgcn_exp2f(St[nt][0]);
        float p1 = __builtin_amdgcn_exp2f(St[nt][1]);
        float p2 = __builtin_amdgcn_exp2f(St[nt][2]);
        float p3 = __builtin_amdgcn_exp2f(St[nt][3]);
        pa[h][nt][k2] = pack2bf_trunc(p0, p1);
        pa[h][nt][k2 + 1] = pack2bf_trunc(p2, p3);
      }
    }
#pragma unroll
    for (int h = 0; h < 2; h++) {
#pragma unroll
      for (int dt = 0; dt < 4; dt++) {
        bf16x8 vb = ldfrag(&Vl[cur][dt * 16 + lr][((h * 4 + quad) ^ (lr & 7)) * 8]);
        __builtin_amdgcn_s_setprio(1);
#pragma unroll
        for (int mt = 0; mt < 2; mt++)
          O[mt][dt] = __builtin_amdgcn_mfma_f32_16x16x32_bf16(
              __builtin_bit_cast(bf16x8, pa[h][mt]), vb, O[mt][dt], 0, 0, 0);
        __builtin_amdgcn_s_setprio(0);
      }
#pragma unroll
      for (int mt = 0; mt < 2; mt++)
        lacc[mt] = __builtin_amdgcn_mfma_f32_16x16x32_bf16(
            __builtin_bit_cast(bf16x8, pa[h][mt]), ones, lacc[mt], 0, 0, 0);
    }
    __syncthreads();
  }

  // epilogue: normalize by l, write bf16 AO
#pragma unroll
  for (int mt = 0; mt < 2; mt++)
#pragma unroll
    for (int rg = 0; rg < 4; rg++) {
      float inv = 1.0f / lacc[mt][rg];
      int s = qbase + mt * 16 + quad * 4 + rg;
#pragma unroll
      for (int dt = 0; dt < 4; dt++)
        AO[((size_t)(b_ * Ss + s) << 8) + head * 64 + dt * 16 + lr] = f2bf(O[mt][dt][rg] * inv);
    }
}

// ---------------- kernel 3: oproj GEMM  y^T = w_o * ao^T + b_o ----------------
// 64(m) x 128(n) tiles, grid (128,4) = 512 blocks -> 2 blocks/CU, 2 waves/SIMD (was 1/1:
// a latency-exposed GEMM with zero TLP). B tiles (ao) shared across the 4 m-blocks via L2.
__global__ __launch_bounds__(256) void k_oproj(const u16* __restrict__ wo, const u16* __restrict__ ao,
                                               const float* __restrict__ bo, float* __restrict__ y) {
  __shared__ u16 As[64][40], Bs[128][40];
  const int tid = threadIdx.x;
  const int wv = tid >> 6, lane = tid & 63;
  const int wm = wv >> 1, wn = wv & 1;
  const int lr = lane & 15, quad = lane >> 4;
  const int n0 = blockIdx.x * 128;
  const int m0 = blockIdx.y * 64;
  f32x4 acc[2][4] = {};
  for (int k0 = 0; k0 < 256; k0 += 32) {
    __syncthreads();
    {  // A: 64 rows x 32 cols (1 seg/thread)
      int row = tid >> 2, seg = tid & 3;
      *(u16x8*)&As[row][seg * 8] = *(const u16x8*)(wo + (m0 + row) * 256 + k0 + seg * 8);
    }
#pragma unroll
    for (int e = 0; e < 2; e++) {  // B: 128 rows x 32 cols
      int c = tid + e * 256;
      int row = c >> 2, seg = c & 3;
      *(u16x8*)&Bs[row][seg * 8] = *(const u16x8*)(ao + ((size_t)(n0 + row) << 8) + k0 + seg * 8);
    }
    __syncthreads();
    bf16x8 a[2], b[4];
#pragma unroll
    for (int mt = 0; mt < 2; mt++) a[mt] = ldfrag(&As[wm * 32 + mt * 16 + lr][quad * 8]);
#pragma unroll
    for (int nt = 0; nt < 4; nt++) b[nt] = ldfrag(&Bs[wn * 64 + nt * 16 + lr][quad * 8]);
#pragma unroll
    for (int mt = 0; mt < 2; mt++)
#pragma unroll
      for (int nt = 0; nt < 4; nt++)
        acc[mt][nt] = __builtin_amdgcn_mfma_f32_16x16x32_bf16(a[mt], b[nt], acc[mt][nt], 0, 0, 0);
  }
#pragma unroll
  for (int mt = 0; mt < 2; mt++)
#pragma unroll
    for (int rg = 0; rg < 4; rg++) {
      int c = m0 + wm * 32 + mt * 16 + quad * 4 + rg;
      float bc = bo[c];
#pragma unroll
      for (int nt = 0; nt < 4; nt++) {
        int col = n0 + wn * 64 + nt * 16 + lr;
        int b_ = col >> 12, s = col & 4095;
        y[((size_t)(b_ * Cc + c) << 12) + s] = acc[mt][nt][rg] + bc;
      }
    }
}

extern "C" void kernel_launch(void* const* d_in, const int* in_sizes, int n_in,
                              void* d_out, int out_size, void* d_ws, size_t ws_size,
                              hipStream_t stream) {
  const float* x = (const float*)d_in[0];
  const float* w_qkv = (const float*)d_in[1];
  const float* b_qkv = (const float*)d_in[2];
  const float* w_o = (const float*)d_in[3];
  const float* b_o = (const float*)d_in[4];
  float* y = (float*)d_out;
  u16* ws = (u16*)d_ws;
  u16* xt = ws;                        // [0, E) — dead after k_qkv; reused as ao
  u16* q = ws + (size_t)ELEMS;
  u16* k = ws + (size_t)2 * ELEMS;
  u16* vt = ws + (size_t)3 * ELEMS;
  u16* ao = xt;
  u16* wqb = ws + (size_t)4 * ELEMS;   // 196608
  u16* wob = wqb + 196608;             // 65536

  k_transpose<<<dim3(64, 4, 4), 256, 0, stream>>>(x, xt, w_qkv, w_o, wqb, wob);
  k_qkv<<<dim3(128, 6), 256, 0, stream>>>(xt, wqb, b_qkv, q, k, vt);
  k_attn<<<dim3(16, 16), 512, 0, stream>>>(q, k, vt, ao);
  k_oproj<<<dim3(128, 4), 256, 0, stream>>>(wob, ao, b_o, y);
}

// Round 9
// 180.707 us; speedup vs baseline: 1.0598x; 1.0598x over previous
//
#include <hip/hip_runtime.h>
#include <stdint.h>

#define DI __device__ __forceinline__

typedef __attribute__((ext_vector_type(8))) __bf16 bf16x8;
typedef __attribute__((ext_vector_type(8))) unsigned short u16x8;
typedef __attribute__((ext_vector_type(4))) float f32x4;
typedef __attribute__((ext_vector_type(4))) uint32_t u32x4;
typedef unsigned short u16;

constexpr int Bb = 4, Cc = 256, Ss = 4096, HD = 64;
constexpr int ELEMS = Bb * Cc * Ss;  // 4194304

DI float bf2f(u16 h) { union { unsigned u; float f; } x; x.u = ((unsigned)h) << 16; return x.f; }
DI u16 f2bf(float f) {
  union { float f; unsigned u; } x; x.f = f;
  return (u16)((x.u + 0x7FFFu + ((x.u >> 16) & 1u)) >> 16);
}
DI uint32_t pack2bf_trunc(float a, float b) {  // low16=bf(a), high16=bf(b), truncating
  union { float f; uint32_t u; } xa, xb;
  xa.f = a; xb.f = b;
  return __builtin_amdgcn_perm(xb.u, xa.u, 0x07060302u);
}
DI bf16x8 ldfrag(const u16* p) { return __builtin_bit_cast(bf16x8, *(const u16x8*)p); }

// async global->LDS DMA, 16B per lane. LDS dest = wave-uniform base + lane*16 (linear);
// source address is per-lane (carries the swizzle).
DI void g2l16(const u16* g, u16* l) {
  __builtin_amdgcn_global_load_lds((const __attribute__((address_space(1))) uint32_t*)(const void*)g,
                                   (__attribute__((address_space(3))) uint32_t*)(void*)l, 16, 0, 0);
}

// ---------------- kernel 0: x (B,C,S) fp32 -> xt (B,S,C) bf16; + weight conversion fused ----------------
__global__ __launch_bounds__(256) void k_transpose(const float* __restrict__ x, u16* __restrict__ xt,
                                                   const float* __restrict__ wq, const float* __restrict__ wo,
                                                   u16* __restrict__ wqb, u16* __restrict__ wob) {
  __shared__ u16 T[64][72];
  const int st = blockIdx.x, ct = blockIdx.y, b = blockIdx.z;
  const int tid = threadIdx.x;
  // fused weight conversion: 1024 blocks x 256 threads == 262144 == 196608 + 65536
  {
    int flat = blockIdx.x + 64 * blockIdx.y + 256 * blockIdx.z;
    int widx = flat * 256 + tid;
    if (widx < 196608) wqb[widx] = f2bf(wq[widx]);
    else wob[widx - 196608] = f2bf(wo[widx - 196608]);
  }
#pragma unroll
  for (int e = 0; e < 2; e++) {
    int ss = tid + e * 256;
    int r = ss >> 3, seg = ss & 7;
    size_t base = ((size_t)(b * Cc + ct * 64 + r) << 12) + st * 64 + seg * 8;
    const float4* xv = (const float4*)(x + base);
    float4 v0 = xv[0], v1 = xv[1];
    u16x8 t;
    t[0] = f2bf(v0.x); t[1] = f2bf(v0.y); t[2] = f2bf(v0.z); t[3] = f2bf(v0.w);
    t[4] = f2bf(v1.x); t[5] = f2bf(v1.y); t[6] = f2bf(v1.z); t[7] = f2bf(v1.w);
    *(u16x8*)&T[r][(seg ^ ((r >> 3) & 7)) * 8] = t;
  }
  __syncthreads();
#pragma unroll
  for (int e = 0; e < 2; e++) {
    int ss = tid + e * 256;
    int sr = ss >> 3, cseg = ss & 7;
    u16x8 o;
#pragma unroll
    for (int j = 0; j < 8; j++) {
      int row = cseg * 8 + j;
      o[j] = T[row][(((sr >> 3) ^ cseg) * 8) + (sr & 7)];
    }
    *(u16x8*)(xt + ((size_t)(b * Ss + st * 64 + sr) << 8) + ct * 64 + cseg * 8) = o;
  }
}

// ---- shared GEMM staging: rows [r0,r0+128) x cols [k0,k0+32), pitch-40 LDS ----
DI void stage_tile(const u16* __restrict__ src, int pitch, int r0, int k0, u16 (*dst)[40], int tid) {
#pragma unroll
  for (int e = 0; e < 2; e++) {
    int c = tid + e * 256;
    int row = c >> 2, seg = c & 3;
    u16x8 t = *(const u16x8*)(src + (size_t)(r0 + row) * pitch + k0 + seg * 8);
    *(u16x8*)&dst[row][seg * 8] = t;
  }
}

// ---------------- kernel 1: qkv GEMM + fused output layouts ----------------
// q:[bh][s][64]*(0.125*log2e)  k:[bh][s][64]  v -> vt [bh][d][chunk*64+slot] directly.
// ALL epilogues route through the LDS tile for vectorized u16x8 stores.
__global__ __launch_bounds__(256) void k_qkv(const u16* __restrict__ xt, const u16* __restrict__ w,
                                             const float* __restrict__ bias,
                                             u16* __restrict__ q, u16* __restrict__ kk_, u16* __restrict__ vt) {
  __shared__ union {
    u16 ab[2][128][40];   // As, Bs during K-loop
    u16 tile[128][136];   // epilogue staging (pitch 136: 16B-aligned rows, conflict-benign)
  } sm;
  const int tid = threadIdx.x;
  const int wv = tid >> 6, lane = tid & 63;
  const int wm = wv >> 1, wn = wv & 1;
  const int lr = lane & 15, quad = lane >> 4;
  const int r0 = blockIdx.x * 128;
  const int j0 = blockIdx.y * 128;
  f32x4 acc[4][4] = {};
  for (int k0 = 0; k0 < 256; k0 += 32) {
    __syncthreads();
    stage_tile(xt, 256, r0, k0, sm.ab[0], tid);
    stage_tile(w, 256, j0, k0, sm.ab[1], tid);
    __syncthreads();
    bf16x8 a[4], b[4];
#pragma unroll
    for (int mt = 0; mt < 4; mt++) a[mt] = ldfrag(&sm.ab[0][wm * 64 + mt * 16 + lr][quad * 8]);
#pragma unroll
    for (int nt = 0; nt < 4; nt++) b[nt] = ldfrag(&sm.ab[1][wn * 64 + nt * 16 + lr][quad * 8]);
#pragma unroll
    for (int mt = 0; mt < 4; mt++)
#pragma unroll
      for (int nt = 0; nt < 4; nt++)
        acc[mt][nt] = __builtin_amdgcn_mfma_f32_16x16x32_bf16(a[mt], b[nt], acc[mt][nt], 0, 0, 0);
  }
  float bj[4];
#pragma unroll
  for (int nt = 0; nt < 4; nt++) bj[nt] = bias[j0 + wn * 64 + nt * 16 + lr];
  __syncthreads();  // drain last ldfrags before overwriting the union
  if (blockIdx.y < 4) {
    // q/k path: stage (acc+bias)*sc to LDS, then coalesced u16x8 stores
    const int part = blockIdx.y >> 1;  // 0=q, 1=k
    u16* outp = part ? kk_ : q;
    const float sc = part ? 1.0f : 0.18033688f;  // 0.125*log2(e), exp2-domain scores
#pragma unroll
    for (int nt = 0; nt < 4; nt++) {
      int lc = wn * 64 + nt * 16 + lr;
#pragma unroll
      for (int mt = 0; mt < 4; mt++)
#pragma unroll
        for (int rg = 0; rg < 4; rg++)
          sm.tile[wm * 64 + mt * 16 + quad * 4 + rg][lc] = f2bf((acc[mt][nt][rg] + bj[nt]) * sc);
    }
    __syncthreads();
    const int hb2 = (blockIdx.y & 1) * 2;  // head base within part
#pragma unroll
    for (int it = 0; it < 8; it++) {
      int seg = tid + it * 256;            // 2048 u16x8 segments
      int row = seg >> 4, cs = seg & 15;   // consecutive tids -> consecutive cols (coalesced)
      u16x8 o = *(const u16x8*)&sm.tile[row][cs * 8];
      int head = hb2 + (cs >> 3), d0 = (cs & 7) * 8;
      int rr = r0 + row, b_ = rr >> 12, s = rr & 4095;
      *(u16x8*)(outp + ((size_t)((b_ * 4 + head) * Ss + s) << 6) + d0) = o;
    }
  } else {
    // v path: acc tile -> LDS -> transposed+permuted vt write
    const int hb = (blockIdx.y - 4) * 2;  // head base (0 or 2)
#pragma unroll
    for (int nt = 0; nt < 4; nt++) {
      int lc = wn * 64 + nt * 16 + lr;
#pragma unroll
      for (int mt = 0; mt < 4; mt++)
#pragma unroll
        for (int rg = 0; rg < 4; rg++)
          sm.tile[wm * 64 + mt * 16 + quad * 4 + rg][lc] = f2bf(acc[mt][nt][rg] + bj[nt]);
    }
    __syncthreads();
    const int b2 = r0 >> 12, sbase = r0 & 4095;
#pragma unroll
    for (int it = 0; it < 8; it++) {
      int seg = tid + it * 256;        // 2048 u16x8 segments
      int sq = seg & 15, hd = seg >> 4;  // consecutive tids -> consecutive slots (coalesced)
      int c = sq >> 3, s8 = sq & 7;
      u16x8 o;
#pragma unroll
      for (int j = 0; j < 8; j++) {
        int slot = s8 * 8 + j;
        int sw = (((slot >> 5) & 1) << 5) | (((slot >> 2) & 1) << 4) |
                 (((slot >> 3) & 3) << 2) | (slot & 3);  // k_vt's w6 bijection
        o[j] = sm.tile[c * 64 + sw][hd];
      }
      int head = hb + (hd >> 6), d = hd & 63;
      *(u16x8*)(vt + ((size_t)((b2 * 4 + head) * 64 + d) << 12) + sbase + c * 64 + s8 * 8) = o;
    }
  }
}

// ---------------- kernel 2: flash attention, S^T form, exp2 no-max softmax ----------------
// nsplit=1 with a Q-SPLIT for occupancy: 512-thread blocks of 16-q waves (128 q/block),
// grid (32,16) = 512 blocks = 2 blocks/CU. r8 showed the controlling variable is barrier-
// domain count (1 block/CU: 99us, MfmaUtil 32; 2 blocks/CU: 77us, 43) — during one block's
// chunk-end vmcnt(0)+barrier drain the other block's waves keep the pipes fed. Q-split keeps
// nsplit=1's wins (no combine, no AOP/lpart traffic, direct normalized AO write) at the cost
// of K/V being fetched by 8 q-blocks per bh instead of 4 (~+35 MB, L2-resident).
// Per-CU invariants vs r6 (best): same MFMA count, same staging issue count.
__global__ __launch_bounds__(512, 4) void k_attn(const u16* __restrict__ Q, const u16* __restrict__ K,
                                                 const u16* __restrict__ VT, u16* __restrict__ AO) {
  __shared__ u16 Kl[2][64][64];
  __shared__ u16 Vl[2][64][64];
  const int tid = threadIdx.x;
  const int wv = tid >> 6, lane = tid & 63;
  const int lr = lane & 15, quad = lane >> 4;
  const int bh = blockIdx.y;
  const int b_ = bh >> 2, head = bh & 3;
  const int qbase = blockIdx.x * 128 + wv * 16;
  const u16* Qh = Q + (size_t)bh * Ss * HD;
  const u16* Kh = K + (size_t)bh * Ss * HD;
  const u16* Vh = VT + (size_t)bh * HD * Ss;  // [d][perm(s)]

  bf16x8 qb[2];
#pragma unroll
  for (int ks = 0; ks < 2; ks++)
    qb[ks] = ldfrag(Qh + (size_t)(qbase + lr) * HD + ks * 32 + quad * 8);

  u16x8 ov;
#pragma unroll
  for (int j = 0; j < 8; j++) ov[j] = 0x3F80;
  const bf16x8 ones = __builtin_bit_cast(bf16x8, ov);

  f32x4 O[4] = {};
  f32x4 lacc = {};

  // DMA staging: 8 waves cover 64 rows (wave wv: rows wv*8..wv*8+7). Lane l writes LDS
  // granule (row = wv*8 + l>>3, slot = l&7); source granule = (l&7) ^ (row&7) = (l&7)^(l>>3).
  const int srow = wv * 8 + (lane >> 3);
  const int sseg = ((lane & 7) ^ (lane >> 3)) * 8;
  const u16* pK = Kh + ((size_t)srow << 6) + sseg;
  const u16* pV = Vh + ((size_t)srow << 12) + sseg;
  auto stage = [&](int buf) {
    g2l16(pK, &Kl[buf][wv * 8][0]);
    g2l16(pV, &Vl[buf][wv * 8][0]);
    pK += 4096; pV += 64;  // next chunk
  };

  stage(0);
  __syncthreads();

  for (int kc = 0; kc < 64; kc++) {
    const int cur = kc & 1;
    if (kc + 1 < 64) stage(cur ^ 1);  // async into other buffer; drains at loop-end barrier

    u32x4 pa[2];  // [kv-half]: packed bf16 P fragments (PV A-operands)
#pragma unroll
    for (int t = 0; t < 4; t++) {  // 16-row kv tiles
      const int krow = t * 16 + lr;
      bf16x8 ka0 = ldfrag(&Kl[cur][krow][(quad ^ (lr & 7)) * 8]);
      bf16x8 ka1 = ldfrag(&Kl[cur][krow][((4 + quad) ^ (lr & 7)) * 8]);
      f32x4 St = {};
      __builtin_amdgcn_s_setprio(1);
      St = __builtin_amdgcn_mfma_f32_16x16x32_bf16(ka0, qb[0], St, 0, 0, 0);
      St = __builtin_amdgcn_mfma_f32_16x16x32_bf16(ka1, qb[1], St, 0, 0, 0);
      __builtin_amdgcn_s_setprio(0);
      const int h = t >> 1, k2 = (t & 1) * 2;
      float p0 = __builtin_amdgcn_exp2f(St[0]);
      float p1 = __builtin_amdgcn_exp2f(St[1]);
      float p2 = __builtin_amdgcn_exp2f(St[2]);
      float p3 = __builtin_amdgcn_exp2f(St[3]);
      pa[h][k2] = pack2bf_trunc(p0, p1);
      pa[h][k2 + 1] = pack2bf_trunc(p2, p3);
    }
#pragma unroll
    for (int h = 0; h < 2; h++) {
      const bf16x8 pah = __builtin_bit_cast(bf16x8, pa[h]);
#pragma unroll
      for (int dt = 0; dt < 4; dt++) {
        bf16x8 vb = ldfrag(&Vl[cur][dt * 16 + lr][((h * 4 + quad) ^ (lr & 7)) * 8]);
        __builtin_amdgcn_s_setprio(1);
        O[dt] = __builtin_amdgcn_mfma_f32_16x16x32_bf16(pah, vb, O[dt], 0, 0, 0);
        __builtin_amdgcn_s_setprio(0);
      }
      lacc = __builtin_amdgcn_mfma_f32_16x16x32_bf16(pah, ones, lacc, 0, 0, 0);
    }
    __syncthreads();
  }

  // epilogue: normalize by l, write bf16 AO
#pragma unroll
  for (int rg = 0; rg < 4; rg++) {
    float inv = 1.0f / lacc[rg];
    int s = qbase + quad * 4 + rg;
#pragma unroll
    for (int dt = 0; dt < 4; dt++)
      AO[((size_t)(b_ * Ss + s) << 8) + head * 64 + dt * 16 + lr] = f2bf(O[dt][rg] * inv);
  }
}

// ---------------- kernel 3: oproj GEMM  y^T = w_o * ao^T + b_o ----------------
// 64(m) x 128(n) tiles, grid (128,4) = 512 blocks -> 2 blocks/CU, 2 waves/SIMD.
__global__ __launch_bounds__(256) void k_oproj(const u16* __restrict__ wo, const u16* __restrict__ ao,
                                               const float* __restrict__ bo, float* __restrict__ y) {
  __shared__ u16 As[64][40], Bs[128][40];
  const int tid = threadIdx.x;
  const int wv = tid >> 6, lane = tid & 63;
  const int wm = wv >> 1, wn = wv & 1;
  const int lr = lane & 15, quad = lane >> 4;
  const int n0 = blockIdx.x * 128;
  const int m0 = blockIdx.y * 64;
  f32x4 acc[2][4] = {};
  for (int k0 = 0; k0 < 256; k0 += 32) {
    __syncthreads();
    {  // A: 64 rows x 32 cols (1 seg/thread)
      int row = tid >> 2, seg = tid & 3;
      *(u16x8*)&As[row][seg * 8] = *(const u16x8*)(wo + (m0 + row) * 256 + k0 + seg * 8);
    }
#pragma unroll
    for (int e = 0; e < 2; e++) {  // B: 128 rows x 32 cols
      int c = tid + e * 256;
      int row = c >> 2, seg = c & 3;
      *(u16x8*)&Bs[row][seg * 8] = *(const u16x8*)(ao + ((size_t)(n0 + row) << 8) + k0 + seg * 8);
    }
    __syncthreads();
    bf16x8 a[2], b[4];
#pragma unroll
    for (int mt = 0; mt < 2; mt++) a[mt] = ldfrag(&As[wm * 32 + mt * 16 + lr][quad * 8]);
#pragma unroll
    for (int nt = 0; nt < 4; nt++) b[nt] = ldfrag(&Bs[wn * 64 + nt * 16 + lr][quad * 8]);
#pragma unroll
    for (int mt = 0; mt < 2; mt++)
#pragma unroll
      for (int nt = 0; nt < 4; nt++)
        acc[mt][nt] = __builtin_amdgcn_mfma_f32_16x16x32_bf16(a[mt], b[nt], acc[mt][nt], 0, 0, 0);
  }
#pragma unroll
  for (int mt = 0; mt < 2; mt++)
#pragma unroll
    for (int rg = 0; rg < 4; rg++) {
      int c = m0 + wm * 32 + mt * 16 + quad * 4 + rg;
      float bc = bo[c];
#pragma unroll
      for (int nt = 0; nt < 4; nt++) {
        int col = n0 + wn * 64 + nt * 16 + lr;
        int b_ = col >> 12, s = col & 4095;
        y[((size_t)(b_ * Cc + c) << 12) + s] = acc[mt][nt][rg] + bc;
      }
    }
}

extern "C" void kernel_launch(void* const* d_in, const int* in_sizes, int n_in,
                              void* d_out, int out_size, void* d_ws, size_t ws_size,
                              hipStream_t stream) {
  const float* x = (const float*)d_in[0];
  const float* w_qkv = (const float*)d_in[1];
  const float* b_qkv = (const float*)d_in[2];
  const float* w_o = (const float*)d_in[3];
  const float* b_o = (const float*)d_in[4];
  float* y = (float*)d_out;
  u16* ws = (u16*)d_ws;
  u16* xt = ws;                        // [0, E) — dead after k_qkv; reused as ao
  u16* q = ws + (size_t)ELEMS;
  u16* k = ws + (size_t)2 * ELEMS;
  u16* vt = ws + (size_t)3 * ELEMS;
  u16* ao = xt;
  u16* wqb = ws + (size_t)4 * ELEMS;   // 196608
  u16* wob = wqb + 196608;             // 65536

  k_transpose<<<dim3(64, 4, 4), 256, 0, stream>>>(x, xt, w_qkv, w_o, wqb, wob);
  k_qkv<<<dim3(128, 6), 256, 0, stream>>>(xt, wqb, b_qkv, q, k, vt);
  k_attn<<<dim3(32, 16), 512, 0, stream>>>(q, k, vt, ao);
  k_oproj<<<dim3(128, 4), 256, 0, stream>>>(wob, ao, b_o, y);
}

// Round 10
// 172.813 us; speedup vs baseline: 1.1082x; 1.0457x over previous
//
#include <hip/hip_runtime.h>
#include <stdint.h>

#define DI __device__ __forceinline__

typedef __attribute__((ext_vector_type(8))) __bf16 bf16x8;
typedef __attribute__((ext_vector_type(8))) unsigned short u16x8;
typedef __attribute__((ext_vector_type(4))) float f32x4;
typedef __attribute__((ext_vector_type(4))) uint32_t u32x4;
typedef unsigned short u16;

constexpr int Bb = 4, Cc = 256, Ss = 4096, HD = 64;
constexpr int ELEMS = Bb * Cc * Ss;  // 4194304

DI float bf2f(u16 h) { union { unsigned u; float f; } x; x.u = ((unsigned)h) << 16; return x.f; }
DI u16 f2bf(float f) {
  union { float f; unsigned u; } x; x.f = f;
  return (u16)((x.u + 0x7FFFu + ((x.u >> 16) & 1u)) >> 16);
}
DI uint32_t pack2bf_trunc(float a, float b) {  // low16=bf(a), high16=bf(b), truncating
  union { float f; uint32_t u; } xa, xb;
  xa.f = a; xb.f = b;
  return __builtin_amdgcn_perm(xb.u, xa.u, 0x07060302u);
}
DI bf16x8 ldfrag(const u16* p) { return __builtin_bit_cast(bf16x8, *(const u16x8*)p); }

// async global->LDS DMA, 16B per lane. LDS dest = wave-uniform base + lane*16 (linear);
// source address is per-lane (carries the swizzle).
DI void g2l16(const u16* g, u16* l) {
  __builtin_amdgcn_global_load_lds((const __attribute__((address_space(1))) uint32_t*)(const void*)g,
                                   (__attribute__((address_space(3))) uint32_t*)(void*)l, 16, 0, 0);
}

// ---------------- kernel 0: x (B,C,S) fp32 -> xt (B,S,C) bf16; + weight conversion fused ----------------
__global__ __launch_bounds__(256) void k_transpose(const float* __restrict__ x, u16* __restrict__ xt,
                                                   const float* __restrict__ wq, const float* __restrict__ wo,
                                                   u16* __restrict__ wqb, u16* __restrict__ wob) {
  __shared__ u16 T[64][72];
  const int st = blockIdx.x, ct = blockIdx.y, b = blockIdx.z;
  const int tid = threadIdx.x;
  // fused weight conversion: 1024 blocks x 256 threads == 262144 == 196608 + 65536
  {
    int flat = blockIdx.x + 64 * blockIdx.y + 256 * blockIdx.z;
    int widx = flat * 256 + tid;
    if (widx < 196608) wqb[widx] = f2bf(wq[widx]);
    else wob[widx - 196608] = f2bf(wo[widx - 196608]);
  }
#pragma unroll
  for (int e = 0; e < 2; e++) {
    int ss = tid + e * 256;
    int r = ss >> 3, seg = ss & 7;
    size_t base = ((size_t)(b * Cc + ct * 64 + r) << 12) + st * 64 + seg * 8;
    const float4* xv = (const float4*)(x + base);
    float4 v0 = xv[0], v1 = xv[1];
    u16x8 t;
    t[0] = f2bf(v0.x); t[1] = f2bf(v0.y); t[2] = f2bf(v0.z); t[3] = f2bf(v0.w);
    t[4] = f2bf(v1.x); t[5] = f2bf(v1.y); t[6] = f2bf(v1.z); t[7] = f2bf(v1.w);
    *(u16x8*)&T[r][(seg ^ ((r >> 3) & 7)) * 8] = t;
  }
  __syncthreads();
#pragma unroll
  for (int e = 0; e < 2; e++) {
    int ss = tid + e * 256;
    int sr = ss >> 3, cseg = ss & 7;
    u16x8 o;
#pragma unroll
    for (int j = 0; j < 8; j++) {
      int row = cseg * 8 + j;
      o[j] = T[row][(((sr >> 3) ^ cseg) * 8) + (sr & 7)];
    }
    *(u16x8*)(xt + ((size_t)(b * Ss + st * 64 + sr) << 8) + ct * 64 + cseg * 8) = o;
  }
}

// ---- shared GEMM staging: rows [r0,r0+128) x cols [k0,k0+32), pitch-40 LDS ----
DI void stage_tile(const u16* __restrict__ src, int pitch, int r0, int k0, u16 (*dst)[40], int tid) {
#pragma unroll
  for (int e = 0; e < 2; e++) {
    int c = tid + e * 256;
    int row = c >> 2, seg = c & 3;
    u16x8 t = *(const u16x8*)(src + (size_t)(r0 + row) * pitch + k0 + seg * 8);
    *(u16x8*)&dst[row][seg * 8] = t;
  }
}

// ---------------- kernel 1: qkv GEMM + fused output layouts ----------------
// q:[bh][s][64]*(0.125*log2e)  k:[bh][s][64]  v -> vt [bh][d][chunk*64+slot] directly.
// ALL epilogues route through the LDS tile for vectorized u16x8 stores.
__global__ __launch_bounds__(256) void k_qkv(const u16* __restrict__ xt, const u16* __restrict__ w,
                                             const float* __restrict__ bias,
                                             u16* __restrict__ q, u16* __restrict__ kk_, u16* __restrict__ vt) {
  __shared__ union {
    u16 ab[2][128][40];   // As, Bs during K-loop
    u16 tile[128][136];   // epilogue staging (pitch 136: 16B-aligned rows, conflict-benign)
  } sm;
  const int tid = threadIdx.x;
  const int wv = tid >> 6, lane = tid & 63;
  const int wm = wv >> 1, wn = wv & 1;
  const int lr = lane & 15, quad = lane >> 4;
  const int r0 = blockIdx.x * 128;
  const int j0 = blockIdx.y * 128;
  f32x4 acc[4][4] = {};
  for (int k0 = 0; k0 < 256; k0 += 32) {
    __syncthreads();
    stage_tile(xt, 256, r0, k0, sm.ab[0], tid);
    stage_tile(w, 256, j0, k0, sm.ab[1], tid);
    __syncthreads();
    bf16x8 a[4], b[4];
#pragma unroll
    for (int mt = 0; mt < 4; mt++) a[mt] = ldfrag(&sm.ab[0][wm * 64 + mt * 16 + lr][quad * 8]);
#pragma unroll
    for (int nt = 0; nt < 4; nt++) b[nt] = ldfrag(&sm.ab[1][wn * 64 + nt * 16 + lr][quad * 8]);
#pragma unroll
    for (int mt = 0; mt < 4; mt++)
#pragma unroll
      for (int nt = 0; nt < 4; nt++)
        acc[mt][nt] = __builtin_amdgcn_mfma_f32_16x16x32_bf16(a[mt], b[nt], acc[mt][nt], 0, 0, 0);
  }
  float bj[4];
#pragma unroll
  for (int nt = 0; nt < 4; nt++) bj[nt] = bias[j0 + wn * 64 + nt * 16 + lr];
  __syncthreads();  // drain last ldfrags before overwriting the union
  if (blockIdx.y < 4) {
    // q/k path: stage (acc+bias)*sc to LDS, then coalesced u16x8 stores
    const int part = blockIdx.y >> 1;  // 0=q, 1=k
    u16* outp = part ? kk_ : q;
    const float sc = part ? 1.0f : 0.18033688f;  // 0.125*log2(e), exp2-domain scores
#pragma unroll
    for (int nt = 0; nt < 4; nt++) {
      int lc = wn * 64 + nt * 16 + lr;
#pragma unroll
      for (int mt = 0; mt < 4; mt++)
#pragma unroll
        for (int rg = 0; rg < 4; rg++)
          sm.tile[wm * 64 + mt * 16 + quad * 4 + rg][lc] = f2bf((acc[mt][nt][rg] + bj[nt]) * sc);
    }
    __syncthreads();
    const int hb2 = (blockIdx.y & 1) * 2;  // head base within part
#pragma unroll
    for (int it = 0; it < 8; it++) {
      int seg = tid + it * 256;            // 2048 u16x8 segments
      int row = seg >> 4, cs = seg & 15;   // consecutive tids -> consecutive cols (coalesced)
      u16x8 o = *(const u16x8*)&sm.tile[row][cs * 8];
      int head = hb2 + (cs >> 3), d0 = (cs & 7) * 8;
      int rr = r0 + row, b_ = rr >> 12, s = rr & 4095;
      *(u16x8*)(outp + ((size_t)((b_ * 4 + head) * Ss + s) << 6) + d0) = o;
    }
  } else {
    // v path: acc tile -> LDS -> transposed+permuted vt write
    const int hb = (blockIdx.y - 4) * 2;  // head base (0 or 2)
#pragma unroll
    for (int nt = 0; nt < 4; nt++) {
      int lc = wn * 64 + nt * 16 + lr;
#pragma unroll
      for (int mt = 0; mt < 4; mt++)
#pragma unroll
        for (int rg = 0; rg < 4; rg++)
          sm.tile[wm * 64 + mt * 16 + quad * 4 + rg][lc] = f2bf(acc[mt][nt][rg] + bj[nt]);
    }
    __syncthreads();
    const int b2 = r0 >> 12, sbase = r0 & 4095;
#pragma unroll
    for (int it = 0; it < 8; it++) {
      int seg = tid + it * 256;        // 2048 u16x8 segments
      int sq = seg & 15, hd = seg >> 4;  // consecutive tids -> consecutive slots (coalesced)
      int c = sq >> 3, s8 = sq & 7;
      u16x8 o;
#pragma unroll
      for (int j = 0; j < 8; j++) {
        int slot = s8 * 8 + j;
        int sw = (((slot >> 5) & 1) << 5) | (((slot >> 2) & 1) << 4) |
                 (((slot >> 3) & 3) << 2) | (slot & 3);  // k_vt's w6 bijection
        o[j] = sm.tile[c * 64 + sw][hd];
      }
      int head = hb + (hd >> 6), d = hd & 63;
      *(u16x8*)(vt + ((size_t)((b2 * 4 + head) * 64 + d) << 12) + sbase + c * 64 + s8 * 8) = o;
    }
  }
}

// ---------------- kernel 2: flash attention, S^T form, exp2 no-max softmax ----------------
// r7's measured-best structure (75.0 us): kv-split nsplit=2, 512-thread blocks, 8 waves of
// 32-q (256 q/block), grid (16,16,2) = 512 blocks = 2 blocks/CU. The design-space map from
// r6-r9: kv-split is the unique point with 2 barrier-domains/CU (during one block's chunk-end
// drain the other feeds the pipes — 1 block/CU costs +22us) AND minimal chunk-instances/CU
// (q-split doubles per-chunk fixed overhead: +12us). Splits write NORMALIZED bf16 partials
// + l; combine is an l-weighted average in k_oproj.
__global__ __launch_bounds__(512, 4) void k_attn(const u16* __restrict__ Q, const u16* __restrict__ K,
                                                 const u16* __restrict__ VT, u16* __restrict__ AO,
                                                 u16* __restrict__ AOP, float* __restrict__ lpart,
                                                 int nsplit) {
  __shared__ u16 Kl[2][64][64];
  __shared__ u16 Vl[2][64][64];
  const int tid = threadIdx.x;
  const int wv = tid >> 6, lane = tid & 63;
  const int lr = lane & 15, quad = lane >> 4;
  const int bh = blockIdx.y;
  const int b_ = bh >> 2, head = bh & 3;
  const int qbase = blockIdx.x * 256 + wv * 32;
  const int sp = blockIdx.z;
  const int nchunk = 64 / nsplit, kcg0 = sp * nchunk;
  const u16* Qh = Q + (size_t)bh * Ss * HD;
  const u16* Kh = K + (size_t)bh * Ss * HD;
  const u16* Vh = VT + (size_t)bh * HD * Ss;  // [d][perm(s)]

  bf16x8 qb[2][2];
#pragma unroll
  for (int nt = 0; nt < 2; nt++)
#pragma unroll
    for (int ks = 0; ks < 2; ks++)
      qb[nt][ks] = ldfrag(Qh + (size_t)(qbase + nt * 16 + lr) * HD + ks * 32 + quad * 8);

  u16x8 ov;
#pragma unroll
  for (int j = 0; j < 8; j++) ov[j] = 0x3F80;
  const bf16x8 ones = __builtin_bit_cast(bf16x8, ov);

  f32x4 O[2][4] = {};
  f32x4 lacc[2] = {};

  // DMA staging: 8 waves cover 64 rows (wave wv: rows wv*8..wv*8+7). Lane l writes LDS
  // granule (row = wv*8 + l>>3, slot = l&7); source granule = (l&7) ^ (row&7) = (l&7)^(l>>3).
  const int srow = wv * 8 + (lane >> 3);
  const int sseg = ((lane & 7) ^ (lane >> 3)) * 8;
  const u16* pK = Kh + ((size_t)(kcg0 * 64 + srow) << 6) + sseg;
  const u16* pV = Vh + ((size_t)srow << 12) + kcg0 * 64 + sseg;
  auto stage = [&](int buf) {
    g2l16(pK, &Kl[buf][wv * 8][0]);
    g2l16(pV, &Vl[buf][wv * 8][0]);
    pK += 4096; pV += 64;  // next chunk
  };

  stage(0);
  __syncthreads();

  for (int kc = 0; kc < nchunk; kc++) {
    const int cur = kc & 1;
    if (kc + 1 < nchunk) stage(cur ^ 1);  // async into other buffer; drains at loop-end barrier

    u32x4 pa[2][2];  // [kv-half][q-group]: packed bf16 P fragments (PV A-operands)
#pragma unroll
    for (int t = 0; t < 4; t++) {  // 16-row kv tiles
      const int krow = t * 16 + lr;
      bf16x8 ka0 = ldfrag(&Kl[cur][krow][(quad ^ (lr & 7)) * 8]);
      bf16x8 ka1 = ldfrag(&Kl[cur][krow][((4 + quad) ^ (lr & 7)) * 8]);
      f32x4 St[2] = {};
      __builtin_amdgcn_s_setprio(1);
#pragma unroll
      for (int nt = 0; nt < 2; nt++)
        St[nt] = __builtin_amdgcn_mfma_f32_16x16x32_bf16(ka0, qb[nt][0], St[nt], 0, 0, 0);
#pragma unroll
      for (int nt = 0; nt < 2; nt++)
        St[nt] = __builtin_amdgcn_mfma_f32_16x16x32_bf16(ka1, qb[nt][1], St[nt], 0, 0, 0);
      __builtin_amdgcn_s_setprio(0);
      const int h = t >> 1, k2 = (t & 1) * 2;
#pragma unroll
      for (int nt = 0; nt < 2; nt++) {
        float p0 = __builtin_amdgcn_exp2f(St[nt][0]);
        float p1 = __builtin_amdgcn_exp2f(St[nt][1]);
        float p2 = __builtin_amdgcn_exp2f(St[nt][2]);
        float p3 = __builtin_amdgcn_exp2f(St[nt][3]);
        pa[h][nt][k2] = pack2bf_trunc(p0, p1);
        pa[h][nt][k2 + 1] = pack2bf_trunc(p2, p3);
      }
    }
#pragma unroll
    for (int h = 0; h < 2; h++) {
#pragma unroll
      for (int dt = 0; dt < 4; dt++) {
        bf16x8 vb = ldfrag(&Vl[cur][dt * 16 + lr][((h * 4 + quad) ^ (lr & 7)) * 8]);
        __builtin_amdgcn_s_setprio(1);
#pragma unroll
        for (int mt = 0; mt < 2; mt++)
          O[mt][dt] = __builtin_amdgcn_mfma_f32_16x16x32_bf16(
              __builtin_bit_cast(bf16x8, pa[h][mt]), vb, O[mt][dt], 0, 0, 0);
        __builtin_amdgcn_s_setprio(0);
      }
#pragma unroll
      for (int mt = 0; mt < 2; mt++)
        lacc[mt] = __builtin_amdgcn_mfma_f32_16x16x32_bf16(
            __builtin_bit_cast(bf16x8, pa[h][mt]), ones, lacc[mt], 0, 0, 0);
    }
    __syncthreads();
  }

  // epilogue: normalize by this split's l, write bf16 (AO if nsplit==1, else partial slot sp)
  u16* dst = (nsplit == 1) ? AO : (AOP + (size_t)sp * ELEMS);
  if (nsplit > 1 && lr == 0) {
    float* lp = lpart + (size_t)sp * (16 * Ss) + bh * Ss;
#pragma unroll
    for (int mt = 0; mt < 2; mt++)
#pragma unroll
      for (int rg = 0; rg < 4; rg++) lp[qbase + mt * 16 + quad * 4 + rg] = lacc[mt][rg];
  }
#pragma unroll
  for (int mt = 0; mt < 2; mt++)
#pragma unroll
    for (int rg = 0; rg < 4; rg++) {
      float inv = 1.0f / lacc[mt][rg];
      int s = qbase + mt * 16 + quad * 4 + rg;
#pragma unroll
      for (int dt = 0; dt < 4; dt++)
        dst[((size_t)(b_ * Ss + s) << 8) + head * 64 + dt * 16 + lr] = f2bf(O[mt][dt][rg] * inv);
    }
}

// ---------------- kernel 3 (fused combine + oproj): y^T = w_o * combine(aop)^T + b_o ----------------
// 128(m) x 64(n) tiles, grid (256,2) = 512 blocks = 2 blocks/CU, 2 waves/SIMD (r7's combine
// version ran 1 block/CU, 1 wave/SIMD — zero TLP). Total combine work identical to r7
// (each B-element combined exactly 2x). B-staging: 1 u16x8 seg/thread.
__global__ __launch_bounds__(256) void k_oproj(const u16* __restrict__ wo, const u16* __restrict__ ao,
                                               const u16* __restrict__ AOP, const float* __restrict__ lpart,
                                               const float* __restrict__ bo, float* __restrict__ y, int nsplit) {
  __shared__ u16 As[128][40], Bs[64][40];
  const int tid = threadIdx.x;
  const int wv = tid >> 6, lane = tid & 63;
  const int wm = wv >> 1, wn = wv & 1;
  const int lr = lane & 15, quad = lane >> 4;
  const int n0 = blockIdx.x * 64;
  const int m0 = blockIdx.y * 128;
  f32x4 acc[4][2] = {};
  for (int k0 = 0; k0 < 256; k0 += 32) {
    __syncthreads();
    stage_tile(wo, 256, m0, k0, As, tid);
    {  // B: 64 n-rows x 32 c-cols, l-weighted combine of normalized bf16 partials
      int row = tid >> 2, seg = tid & 3;
      int bs = n0 + row, cc = k0 + seg * 8;
      u16x8 t;
      if (nsplit == 1) {
        t = *(const u16x8*)(ao + ((size_t)bs << 8) + cc);
      } else {
        int b = bs >> 12, s = bs & 4095, head = cc >> 6;
        int li = (b * 4 + head) * Ss + s;
        float accv[8] = {0.f, 0.f, 0.f, 0.f, 0.f, 0.f, 0.f, 0.f};
        float lsum = 0.f;
        for (int spl = 0; spl < nsplit; spl++) {
          float l = lpart[(size_t)spl * (16 * Ss) + li];
          u16x8 a = *(const u16x8*)(AOP + (size_t)spl * ELEMS + ((size_t)bs << 8) + cc);
          lsum += l;
#pragma unroll
          for (int i = 0; i < 8; i++) accv[i] += l * bf2f(a[i]);
        }
        float inv = 1.0f / lsum;
#pragma unroll
        for (int i = 0; i < 8; i++) t[i] = f2bf(accv[i] * inv);
      }
      *(u16x8*)&Bs[row][seg * 8] = t;
    }
    __syncthreads();
    bf16x8 a[4], b[2];
#pragma unroll
    for (int mt = 0; mt < 4; mt++) a[mt] = ldfrag(&As[wm * 64 + mt * 16 + lr][quad * 8]);
#pragma unroll
    for (int nt = 0; nt < 2; nt++) b[nt] = ldfrag(&Bs[wn * 32 + nt * 16 + lr][quad * 8]);
#pragma unroll
    for (int mt = 0; mt < 4; mt++)
#pragma unroll
      for (int nt = 0; nt < 2; nt++)
        acc[mt][nt] = __builtin_amdgcn_mfma_f32_16x16x32_bf16(a[mt], b[nt], acc[mt][nt], 0, 0, 0);
  }
#pragma unroll
  for (int mt = 0; mt < 4; mt++)
#pragma unroll
    for (int rg = 0; rg < 4; rg++) {
      int c = m0 + wm * 64 + mt * 16 + quad * 4 + rg;
      float bc = bo[c];
#pragma unroll
      for (int nt = 0; nt < 2; nt++) {
        int col = n0 + wn * 32 + nt * 16 + lr;
        int b_ = col >> 12, s = col & 4095;
        y[((size_t)(b_ * Cc + c) << 12) + s] = acc[mt][nt][rg] + bc;
      }
    }
}

extern "C" void kernel_launch(void* const* d_in, const int* in_sizes, int n_in,
                              void* d_out, int out_size, void* d_ws, size_t ws_size,
                              hipStream_t stream) {
  const float* x = (const float*)d_in[0];
  const float* w_qkv = (const float*)d_in[1];
  const float* b_qkv = (const float*)d_in[2];
  const float* w_o = (const float*)d_in[3];
  const float* b_o = (const float*)d_in[4];
  float* y = (float*)d_out;
  u16* ws = (u16*)d_ws;
  u16* xt = ws;                        // [0, E) — dead after k_qkv; reused as ao (nsplit==1)
  u16* q = ws + (size_t)ELEMS;
  u16* k = ws + (size_t)2 * ELEMS;
  u16* vt = ws + (size_t)3 * ELEMS;
  u16* ao = xt;
  u16* wqb = ws + (size_t)4 * ELEMS;   // 196608
  u16* wob = wqb + 196608;             // 65536
  const size_t Wu16 = (size_t)4 * ELEMS + 262144;
  // need(n) bytes = bf16 ws incl. n partial slabs, + n*16*Ss f32 for lpart
  auto need = [&](int n) { return (Wu16 + (size_t)n * ELEMS) * 2 + (size_t)n * 16 * Ss * 4; };
  const int nsplit = (ws_size >= need(2)) ? 2 : 1;
  u16* aop = ws + Wu16;                // nsplit*ELEMS u16 normalized partials
  float* lpart = (float*)(aop + (size_t)nsplit * ELEMS);

  k_transpose<<<dim3(64, 4, 4), 256, 0, stream>>>(x, xt, w_qkv, w_o, wqb, wob);
  k_qkv<<<dim3(128, 6), 256, 0, stream>>>(xt, wqb, b_qkv, q, k, vt);
  k_attn<<<dim3(16, 16, nsplit), 512, 0, stream>>>(q, k, vt, ao, aop, lpart, nsplit);
  k_oproj<<<dim3(256, 2), 256, 0, stream>>>(wob, ao, aop, lpart, b_o, y, nsplit);
}

// Round 11
// 172.318 us; speedup vs baseline: 1.1114x; 1.0029x over previous
//
#include <hip/hip_runtime.h>
#include <stdint.h>

#define DI __device__ __forceinline__

typedef __attribute__((ext_vector_type(8))) __bf16 bf16x8;
typedef __attribute__((ext_vector_type(8))) unsigned short u16x8;
typedef __attribute__((ext_vector_type(4))) float f32x4;
typedef __attribute__((ext_vector_type(4))) uint32_t u32x4;
typedef unsigned short u16;

constexpr int Bb = 4, Cc = 256, Ss = 4096, HD = 64;
constexpr int ELEMS = Bb * Cc * Ss;  // 4194304

DI float bf2f(u16 h) { union { unsigned u; float f; } x; x.u = ((unsigned)h) << 16; return x.f; }
DI u16 f2bf(float f) {
  union { float f; unsigned u; } x; x.f = f;
  return (u16)((x.u + 0x7FFFu + ((x.u >> 16) & 1u)) >> 16);
}
DI uint32_t pack2bf_trunc(float a, float b) {  // low16=bf(a), high16=bf(b), truncating
  union { float f; uint32_t u; } xa, xb;
  xa.f = a; xb.f = b;
  return __builtin_amdgcn_perm(xb.u, xa.u, 0x07060302u);
}
DI bf16x8 ldfrag(const u16* p) { return __builtin_bit_cast(bf16x8, *(const u16x8*)p); }

// async global->LDS DMA, 16B per lane. LDS dest = wave-uniform base + lane*16 (linear);
// source address is per-lane (carries the swizzle).
DI void g2l16(const u16* g, u16* l) {
  __builtin_amdgcn_global_load_lds((const __attribute__((address_space(1))) uint32_t*)(const void*)g,
                                   (__attribute__((address_space(3))) uint32_t*)(void*)l, 16, 0, 0);
}

// ---------------- kernel 0: x (B,C,S) fp32 -> xt (B,S,C) bf16; + weight conversion fused ----------------
__global__ __launch_bounds__(256) void k_transpose(const float* __restrict__ x, u16* __restrict__ xt,
                                                   const float* __restrict__ wq, const float* __restrict__ wo,
                                                   u16* __restrict__ wqb, u16* __restrict__ wob) {
  __shared__ u16 T[64][72];
  const int st = blockIdx.x, ct = blockIdx.y, b = blockIdx.z;
  const int tid = threadIdx.x;
  // fused weight conversion: 1024 blocks x 256 threads == 262144 == 196608 + 65536
  {
    int flat = blockIdx.x + 64 * blockIdx.y + 256 * blockIdx.z;
    int widx = flat * 256 + tid;
    if (widx < 196608) wqb[widx] = f2bf(wq[widx]);
    else wob[widx - 196608] = f2bf(wo[widx - 196608]);
  }
#pragma unroll
  for (int e = 0; e < 2; e++) {
    int ss = tid + e * 256;
    int r = ss >> 3, seg = ss & 7;
    size_t base = ((size_t)(b * Cc + ct * 64 + r) << 12) + st * 64 + seg * 8;
    const float4* xv = (const float4*)(x + base);
    float4 v0 = xv[0], v1 = xv[1];
    u16x8 t;
    t[0] = f2bf(v0.x); t[1] = f2bf(v0.y); t[2] = f2bf(v0.z); t[3] = f2bf(v0.w);
    t[4] = f2bf(v1.x); t[5] = f2bf(v1.y); t[6] = f2bf(v1.z); t[7] = f2bf(v1.w);
    *(u16x8*)&T[r][(seg ^ ((r >> 3) & 7)) * 8] = t;
  }
  __syncthreads();
#pragma unroll
  for (int e = 0; e < 2; e++) {
    int ss = tid + e * 256;
    int sr = ss >> 3, cseg = ss & 7;
    u16x8 o;
#pragma unroll
    for (int j = 0; j < 8; j++) {
      int row = cseg * 8 + j;
      o[j] = T[row][(((sr >> 3) ^ cseg) * 8) + (sr & 7)];
    }
    *(u16x8*)(xt + ((size_t)(b * Ss + st * 64 + sr) << 8) + ct * 64 + cseg * 8) = o;
  }
}

// ---- shared GEMM staging: rows [r0,r0+128) x cols [k0,k0+32), pitch-40 LDS ----
DI void stage_tile(const u16* __restrict__ src, int pitch, int r0, int k0, u16 (*dst)[40], int tid) {
#pragma unroll
  for (int e = 0; e < 2; e++) {
    int c = tid + e * 256;
    int row = c >> 2, seg = c & 3;
    u16x8 t = *(const u16x8*)(src + (size_t)(r0 + row) * pitch + k0 + seg * 8);
    *(u16x8*)&dst[row][seg * 8] = t;
  }
}

// ---------------- kernel 1: qkv GEMM + fused output layouts ----------------
// q:[bh][s][64]*(0.125*log2e)  k:[bh][s][64]  v -> vt [bh][d][chunk*64+slot] directly.
// ALL epilogues route through the LDS tile for vectorized u16x8 stores.
__global__ __launch_bounds__(256) void k_qkv(const u16* __restrict__ xt, const u16* __restrict__ w,
                                             const float* __restrict__ bias,
                                             u16* __restrict__ q, u16* __restrict__ kk_, u16* __restrict__ vt) {
  __shared__ union {
    u16 ab[2][128][40];   // As, Bs during K-loop
    u16 tile[128][136];   // epilogue staging (pitch 136: 16B-aligned rows, conflict-benign)
  } sm;
  const int tid = threadIdx.x;
  const int wv = tid >> 6, lane = tid & 63;
  const int wm = wv >> 1, wn = wv & 1;
  const int lr = lane & 15, quad = lane >> 4;
  const int r0 = blockIdx.x * 128;
  const int j0 = blockIdx.y * 128;
  f32x4 acc[4][4] = {};
  for (int k0 = 0; k0 < 256; k0 += 32) {
    __syncthreads();
    stage_tile(xt, 256, r0, k0, sm.ab[0], tid);
    stage_tile(w, 256, j0, k0, sm.ab[1], tid);
    __syncthreads();
    bf16x8 a[4], b[4];
#pragma unroll
    for (int mt = 0; mt < 4; mt++) a[mt] = ldfrag(&sm.ab[0][wm * 64 + mt * 16 + lr][quad * 8]);
#pragma unroll
    for (int nt = 0; nt < 4; nt++) b[nt] = ldfrag(&sm.ab[1][wn * 64 + nt * 16 + lr][quad * 8]);
#pragma unroll
    for (int mt = 0; mt < 4; mt++)
#pragma unroll
      for (int nt = 0; nt < 4; nt++)
        acc[mt][nt] = __builtin_amdgcn_mfma_f32_16x16x32_bf16(a[mt], b[nt], acc[mt][nt], 0, 0, 0);
  }
  float bj[4];
#pragma unroll
  for (int nt = 0; nt < 4; nt++) bj[nt] = bias[j0 + wn * 64 + nt * 16 + lr];
  __syncthreads();  // drain last ldfrags before overwriting the union
  if (blockIdx.y < 4) {
    // q/k path: stage (acc+bias)*sc to LDS, then coalesced u16x8 stores
    const int part = blockIdx.y >> 1;  // 0=q, 1=k
    u16* outp = part ? kk_ : q;
    const float sc = part ? 1.0f : 0.18033688f;  // 0.125*log2(e), exp2-domain scores
#pragma unroll
    for (int nt = 0; nt < 4; nt++) {
      int lc = wn * 64 + nt * 16 + lr;
#pragma unroll
      for (int mt = 0; mt < 4; mt++)
#pragma unroll
        for (int rg = 0; rg < 4; rg++)
          sm.tile[wm * 64 + mt * 16 + quad * 4 + rg][lc] = f2bf((acc[mt][nt][rg] + bj[nt]) * sc);
    }
    __syncthreads();
    const int hb2 = (blockIdx.y & 1) * 2;  // head base within part
#pragma unroll
    for (int it = 0; it < 8; it++) {
      int seg = tid + it * 256;            // 2048 u16x8 segments
      int row = seg >> 4, cs = seg & 15;   // consecutive tids -> consecutive cols (coalesced)
      u16x8 o = *(const u16x8*)&sm.tile[row][cs * 8];
      int head = hb2 + (cs >> 3), d0 = (cs & 7) * 8;
      int rr = r0 + row, b_ = rr >> 12, s = rr & 4095;
      *(u16x8*)(outp + ((size_t)((b_ * 4 + head) * Ss + s) << 6) + d0) = o;
    }
  } else {
    // v path: acc tile -> LDS -> transposed+permuted vt write
    const int hb = (blockIdx.y - 4) * 2;  // head base (0 or 2)
#pragma unroll
    for (int nt = 0; nt < 4; nt++) {
      int lc = wn * 64 + nt * 16 + lr;
#pragma unroll
      for (int mt = 0; mt < 4; mt++)
#pragma unroll
        for (int rg = 0; rg < 4; rg++)
          sm.tile[wm * 64 + mt * 16 + quad * 4 + rg][lc] = f2bf(acc[mt][nt][rg] + bj[nt]);
    }
    __syncthreads();
    const int b2 = r0 >> 12, sbase = r0 & 4095;
#pragma unroll
    for (int it = 0; it < 8; it++) {
      int seg = tid + it * 256;        // 2048 u16x8 segments
      int sq = seg & 15, hd = seg >> 4;  // consecutive tids -> consecutive slots (coalesced)
      int c = sq >> 3, s8 = sq & 7;
      u16x8 o;
#pragma unroll
      for (int j = 0; j < 8; j++) {
        int slot = s8 * 8 + j;
        int sw = (((slot >> 5) & 1) << 5) | (((slot >> 2) & 1) << 4) |
                 (((slot >> 3) & 3) << 2) | (slot & 3);  // k_vt's w6 bijection
        o[j] = sm.tile[c * 64 + sw][hd];
      }
      int head = hb + (hd >> 6), d = hd & 63;
      *(u16x8*)(vt + ((size_t)((b2 * 4 + head) * 64 + d) << 12) + sbase + c * 64 + s8 * 8) = o;
    }
  }
}

// ---------------- kernel 2: flash attention, S^T form, exp2 no-max softmax ----------------
// r10 structure (73.9 us) + 128-row kv-chunks: two 64-row sub-tiles per barrier span.
// Per-kv-row work (MFMA, exp2, ds_read, staged bytes) invariant; barrier count halves
// (32 -> 16 per block) and prefetch latency-coverage doubles. r8 measured the chunk-end
// vmcnt(0)+barrier drain as the idle source (~10us residue at 2 domains); this attacks it.
// LDS 64KB (Kl+Vl [2][2][64][64]) -> still 2 blocks/CU (128KB of 160).
__global__ __launch_bounds__(512, 4) void k_attn(const u16* __restrict__ Q, const u16* __restrict__ K,
                                                 const u16* __restrict__ VT, u16* __restrict__ AO,
                                                 u16* __restrict__ AOP, float* __restrict__ lpart,
                                                 int nsplit) {
  __shared__ u16 Kl[2][2][64][64];
  __shared__ u16 Vl[2][2][64][64];
  const int tid = threadIdx.x;
  const int wv = tid >> 6, lane = tid & 63;
  const int lr = lane & 15, quad = lane >> 4;
  const int bh = blockIdx.y;
  const int b_ = bh >> 2, head = bh & 3;
  const int qbase = blockIdx.x * 256 + wv * 32;
  const int sp = blockIdx.z;
  const int nbig = 32 / nsplit, bg0 = sp * nbig;  // big chunks of 128 kv rows
  const u16* Qh = Q + (size_t)bh * Ss * HD;
  const u16* Kh = K + (size_t)bh * Ss * HD;
  const u16* Vh = VT + (size_t)bh * HD * Ss;  // [d][perm(s)]

  bf16x8 qb[2][2];
#pragma unroll
  for (int nt = 0; nt < 2; nt++)
#pragma unroll
    for (int ks = 0; ks < 2; ks++)
      qb[nt][ks] = ldfrag(Qh + (size_t)(qbase + nt * 16 + lr) * HD + ks * 32 + quad * 8);

  u16x8 ov;
#pragma unroll
  for (int j = 0; j < 8; j++) ov[j] = 0x3F80;
  const bf16x8 ones = __builtin_bit_cast(bf16x8, ov);

  f32x4 O[2][4] = {};
  f32x4 lacc[2] = {};

  // DMA staging: per sub-tile, 8 waves cover 64 rows (wave wv: rows wv*8..wv*8+7). Lane l
  // writes LDS granule (row = wv*8 + l>>3, slot = l&7); source granule = (l&7)^(l>>3).
  const int srow = wv * 8 + (lane >> 3);
  const int sseg = ((lane & 7) ^ (lane >> 3)) * 8;
  const u16* pK = Kh + ((size_t)(bg0 * 128 + srow) << 6) + sseg;
  const u16* pV = Vh + ((size_t)srow << 12) + bg0 * 128 + sseg;
  auto stage = [&](int buf) {
#pragma unroll
    for (int s = 0; s < 2; s++) {
      g2l16(pK + (s << 12), &Kl[buf][s][wv * 8][0]);  // sub s: +64 rows * 64 cols
      g2l16(pV + s * 64, &Vl[buf][s][wv * 8][0]);     // sub s: +64 slots
    }
    pK += 8192; pV += 128;  // next big chunk (128 kv rows / 128 slots)
  };

  stage(0);
  __syncthreads();

  for (int bc = 0; bc < nbig; bc++) {
    const int cur = bc & 1;
    if (bc + 1 < nbig) stage(cur ^ 1);  // async into other buffer; drains at loop-end barrier

#pragma unroll
    for (int sub = 0; sub < 2; sub++) {
      u32x4 pa[2][2];  // [kv-half][q-group]: packed bf16 P fragments (PV A-operands)
#pragma unroll
      for (int t = 0; t < 4; t++) {  // 16-row kv tiles within sub
        const int krow = t * 16 + lr;
        bf16x8 ka0 = ldfrag(&Kl[cur][sub][krow][(quad ^ (lr & 7)) * 8]);
        bf16x8 ka1 = ldfrag(&Kl[cur][sub][krow][((4 + quad) ^ (lr & 7)) * 8]);
        f32x4 St[2] = {};
        __builtin_amdgcn_s_setprio(1);
#pragma unroll
        for (int nt = 0; nt < 2; nt++)
          St[nt] = __builtin_amdgcn_mfma_f32_16x16x32_bf16(ka0, qb[nt][0], St[nt], 0, 0, 0);
#pragma unroll
        for (int nt = 0; nt < 2; nt++)
          St[nt] = __builtin_amdgcn_mfma_f32_16x16x32_bf16(ka1, qb[nt][1], St[nt], 0, 0, 0);
        __builtin_amdgcn_s_setprio(0);
        const int h = t >> 1, k2 = (t & 1) * 2;
#pragma unroll
        for (int nt = 0; nt < 2; nt++) {
          float p0 = __builtin_amdgcn_exp2f(St[nt][0]);
          float p1 = __builtin_amdgcn_exp2f(St[nt][1]);
          float p2 = __builtin_amdgcn_exp2f(St[nt][2]);
          float p3 = __builtin_amdgcn_exp2f(St[nt][3]);
          pa[h][nt][k2] = pack2bf_trunc(p0, p1);
          pa[h][nt][k2 + 1] = pack2bf_trunc(p2, p3);
        }
      }
#pragma unroll
      for (int h = 0; h < 2; h++) {
#pragma unroll
        for (int dt = 0; dt < 4; dt++) {
          bf16x8 vb = ldfrag(&Vl[cur][sub][dt * 16 + lr][((h * 4 + quad) ^ (lr & 7)) * 8]);
          __builtin_amdgcn_s_setprio(1);
#pragma unroll
          for (int mt = 0; mt < 2; mt++)
            O[mt][dt] = __builtin_amdgcn_mfma_f32_16x16x32_bf16(
                __builtin_bit_cast(bf16x8, pa[h][mt]), vb, O[mt][dt], 0, 0, 0);
          __builtin_amdgcn_s_setprio(0);
        }
#pragma unroll
        for (int mt = 0; mt < 2; mt++)
          lacc[mt] = __builtin_amdgcn_mfma_f32_16x16x32_bf16(
              __builtin_bit_cast(bf16x8, pa[h][mt]), ones, lacc[mt], 0, 0, 0);
      }
    }
    __syncthreads();
  }

  // epilogue: normalize by this split's l, write bf16 (AO if nsplit==1, else partial slot sp)
  u16* dst = (nsplit == 1) ? AO : (AOP + (size_t)sp * ELEMS);
  if (nsplit > 1 && lr == 0) {
    float* lp = lpart + (size_t)sp * (16 * Ss) + bh * Ss;
#pragma unroll
    for (int mt = 0; mt < 2; mt++)
#pragma unroll
      for (int rg = 0; rg < 4; rg++) lp[qbase + mt * 16 + quad * 4 + rg] = lacc[mt][rg];
  }
#pragma unroll
  for (int mt = 0; mt < 2; mt++)
#pragma unroll
    for (int rg = 0; rg < 4; rg++) {
      float inv = 1.0f / lacc[mt][rg];
      int s = qbase + mt * 16 + quad * 4 + rg;
#pragma unroll
      for (int dt = 0; dt < 4; dt++)
        dst[((size_t)(b_ * Ss + s) << 8) + head * 64 + dt * 16 + lr] = f2bf(O[mt][dt][rg] * inv);
    }
}

// ---------------- kernel 3 (fused combine + oproj): y^T = w_o * combine(aop)^T + b_o ----------------
// 128(m) x 64(n) tiles, grid (256,2) = 512 blocks = 2 blocks/CU, 2 waves/SIMD.
__global__ __launch_bounds__(256) void k_oproj(const u16* __restrict__ wo, const u16* __restrict__ ao,
                                               const u16* __restrict__ AOP, const float* __restrict__ lpart,
                                               const float* __restrict__ bo, float* __restrict__ y, int nsplit) {
  __shared__ u16 As[128][40], Bs[64][40];
  const int tid = threadIdx.x;
  const int wv = tid >> 6, lane = tid & 63;
  const int wm = wv >> 1, wn = wv & 1;
  const int lr = lane & 15, quad = lane >> 4;
  const int n0 = blockIdx.x * 64;
  const int m0 = blockIdx.y * 128;
  f32x4 acc[4][2] = {};
  for (int k0 = 0; k0 < 256; k0 += 32) {
    __syncthreads();
    stage_tile(wo, 256, m0, k0, As, tid);
    {  // B: 64 n-rows x 32 c-cols, l-weighted combine of normalized bf16 partials
      int row = tid >> 2, seg = tid & 3;
      int bs = n0 + row, cc = k0 + seg * 8;
      u16x8 t;
      if (nsplit == 1) {
        t = *(const u16x8*)(ao + ((size_t)bs << 8) + cc);
      } else {
        int b = bs >> 12, s = bs & 4095, head = cc >> 6;
        int li = (b * 4 + head) * Ss + s;
        float accv[8] = {0.f, 0.f, 0.f, 0.f, 0.f, 0.f, 0.f, 0.f};
        float lsum = 0.f;
        for (int spl = 0; spl < nsplit; spl++) {
          float l = lpart[(size_t)spl * (16 * Ss) + li];
          u16x8 a = *(const u16x8*)(AOP + (size_t)spl * ELEMS + ((size_t)bs << 8) + cc);
          lsum += l;
#pragma unroll
          for (int i = 0; i < 8; i++) accv[i] += l * bf2f(a[i]);
        }
        float inv = 1.0f / lsum;
#pragma unroll
        for (int i = 0; i < 8; i++) t[i] = f2bf(accv[i] * inv);
      }
      *(u16x8*)&Bs[row][seg * 8] = t;
    }
    __syncthreads();
    bf16x8 a[4], b[2];
#pragma unroll
    for (int mt = 0; mt < 4; mt++) a[mt] = ldfrag(&As[wm * 64 + mt * 16 + lr][quad * 8]);
#pragma unroll
    for (int nt = 0; nt < 2; nt++) b[nt] = ldfrag(&Bs[wn * 32 + nt * 16 + lr][quad * 8]);
#pragma unroll
    for (int mt = 0; mt < 4; mt++)
#pragma unroll
      for (int nt = 0; nt < 2; nt++)
        acc[mt][nt] = __builtin_amdgcn_mfma_f32_16x16x32_bf16(a[mt], b[nt], acc[mt][nt], 0, 0, 0);
  }
#pragma unroll
  for (int mt = 0; mt < 4; mt++)
#pragma unroll
    for (int rg = 0; rg < 4; rg++) {
      int c = m0 + wm * 64 + mt * 16 + quad * 4 + rg;
      float bc = bo[c];
#pragma unroll
      for (int nt = 0; nt < 2; nt++) {
        int col = n0 + wn * 32 + nt * 16 + lr;
        int b_ = col >> 12, s = col & 4095;
        y[((size_t)(b_ * Cc + c) << 12) + s] = acc[mt][nt][rg] + bc;
      }
    }
}

extern "C" void kernel_launch(void* const* d_in, const int* in_sizes, int n_in,
                              void* d_out, int out_size, void* d_ws, size_t ws_size,
                              hipStream_t stream) {
  const float* x = (const float*)d_in[0];
  const float* w_qkv = (const float*)d_in[1];
  const float* b_qkv = (const float*)d_in[2];
  const float* w_o = (const float*)d_in[3];
  const float* b_o = (const float*)d_in[4];
  float* y = (float*)d_out;
  u16* ws = (u16*)d_ws;
  u16* xt = ws;                        // [0, E) — dead after k_qkv; reused as ao (nsplit==1)
  u16* q = ws + (size_t)ELEMS;
  u16* k = ws + (size_t)2 * ELEMS;
  u16* vt = ws + (size_t)3 * ELEMS;
  u16* ao = xt;
  u16* wqb = ws + (size_t)4 * ELEMS;   // 196608
  u16* wob = wqb + 196608;             // 65536
  const size_t Wu16 = (size_t)4 * ELEMS + 262144;
  // need(n) bytes = bf16 ws incl. n partial slabs, + n*16*Ss f32 for lpart
  auto need = [&](int n) { return (Wu16 + (size_t)n * ELEMS) * 2 + (size_t)n * 16 * Ss * 4; };
  const int nsplit = (ws_size >= need(2)) ? 2 : 1;
  u16* aop = ws + Wu16;                // nsplit*ELEMS u16 normalized partials
  float* lpart = (float*)(aop + (size_t)nsplit * ELEMS);

  k_transpose<<<dim3(64, 4, 4), 256, 0, stream>>>(x, xt, w_qkv, w_o, wqb, wob);
  k_qkv<<<dim3(128, 6), 256, 0, stream>>>(xt, wqb, b_qkv, q, k, vt);
  k_attn<<<dim3(16, 16, nsplit), 512, 0, stream>>>(q, k, vt, ao, aop, lpart, nsplit);
  k_oproj<<<dim3(256, 2), 256, 0, stream>>>(wob, ao, aop, lpart, b_o, y, nsplit);
}

// Round 12
// 167.871 us; speedup vs baseline: 1.1408x; 1.0265x over previous
//
#include <hip/hip_runtime.h>
#include <stdint.h>

#define DI __device__ __forceinline__

typedef __attribute__((ext_vector_type(8))) __bf16 bf16x8;
typedef __attribute__((ext_vector_type(8))) unsigned short u16x8;
typedef __attribute__((ext_vector_type(4))) float f32x4;
typedef __attribute__((ext_vector_type(4))) uint32_t u32x4;
typedef unsigned short u16;

constexpr int Bb = 4, Cc = 256, Ss = 4096, HD = 64;
constexpr int ELEMS = Bb * Cc * Ss;  // 4194304

DI float bf2f(u16 h) { union { unsigned u; float f; } x; x.u = ((unsigned)h) << 16; return x.f; }
DI u16 f2bf(float f) {
  union { float f; unsigned u; } x; x.f = f;
  return (u16)((x.u + 0x7FFFu + ((x.u >> 16) & 1u)) >> 16);
}
DI uint32_t pack2bf_trunc(float a, float b) {  // low16=bf(a), high16=bf(b), truncating
  union { float f; uint32_t u; } xa, xb;
  xa.f = a; xb.f = b;
  return __builtin_amdgcn_perm(xb.u, xa.u, 0x07060302u);
}
DI bf16x8 ldfrag(const u16* p) { return __builtin_bit_cast(bf16x8, *(const u16x8*)p); }

// async global->LDS DMA, 16B per lane. LDS dest = wave-uniform base + lane*16 (linear);
// source address is per-lane (carries the swizzle).
DI void g2l16(const u16* g, u16* l) {
  __builtin_amdgcn_global_load_lds((const __attribute__((address_space(1))) uint32_t*)(const void*)g,
                                   (__attribute__((address_space(3))) uint32_t*)(void*)l, 16, 0, 0);
}

// ---------------- kernel 0: x (B,C,S) fp32 -> xt (B,S,C) bf16; + weight conversion fused ----------------
__global__ __launch_bounds__(256) void k_transpose(const float* __restrict__ x, u16* __restrict__ xt,
                                                   const float* __restrict__ wq, const float* __restrict__ wo,
                                                   u16* __restrict__ wqb, u16* __restrict__ wob) {
  __shared__ u16 T[64][72];
  const int st = blockIdx.x, ct = blockIdx.y, b = blockIdx.z;
  const int tid = threadIdx.x;
  // fused weight conversion: 1024 blocks x 256 threads == 262144 == 196608 + 65536
  {
    int flat = blockIdx.x + 64 * blockIdx.y + 256 * blockIdx.z;
    int widx = flat * 256 + tid;
    if (widx < 196608) wqb[widx] = f2bf(wq[widx]);
    else wob[widx - 196608] = f2bf(wo[widx - 196608]);
  }
#pragma unroll
  for (int e = 0; e < 2; e++) {
    int ss = tid + e * 256;
    int r = ss >> 3, seg = ss & 7;
    size_t base = ((size_t)(b * Cc + ct * 64 + r) << 12) + st * 64 + seg * 8;
    const float4* xv = (const float4*)(x + base);
    float4 v0 = xv[0], v1 = xv[1];
    u16x8 t;
    t[0] = f2bf(v0.x); t[1] = f2bf(v0.y); t[2] = f2bf(v0.z); t[3] = f2bf(v0.w);
    t[4] = f2bf(v1.x); t[5] = f2bf(v1.y); t[6] = f2bf(v1.z); t[7] = f2bf(v1.w);
    *(u16x8*)&T[r][(seg ^ ((r >> 3) & 7)) * 8] = t;
  }
  __syncthreads();
#pragma unroll
  for (int e = 0; e < 2; e++) {
    int ss = tid + e * 256;
    int sr = ss >> 3, cseg = ss & 7;
    u16x8 o;
#pragma unroll
    for (int j = 0; j < 8; j++) {
      int row = cseg * 8 + j;
      o[j] = T[row][(((sr >> 3) ^ cseg) * 8) + (sr & 7)];
    }
    *(u16x8*)(xt + ((size_t)(b * Ss + st * 64 + sr) << 8) + ct * 64 + cseg * 8) = o;
  }
}

// ---------------- kernel 1: qkv GEMM + fused output layouts ----------------
// q:[bh][s][64]*(0.125*log2e)  k:[bh][s][64]  v -> vt [bh][d][chunk*64+slot] directly.
// Staging rebuilt on the k_attn-proven pattern: linear [128][32] LDS tiles, double-buffered,
// global_load_lds DMA (4/thread/K-step) with pre-swizzled source granule g^(row&3), ONE
// barrier per K-step (was 2), DMA overlapped with MFMA. Frag reads use the same XOR ->
// all 32 banks covered evenly (conflict-free b128). Epilogues unchanged (LDS-staged stores).
__global__ __launch_bounds__(256) void k_qkv(const u16* __restrict__ xt, const u16* __restrict__ w,
                                             const float* __restrict__ bias,
                                             u16* __restrict__ q, u16* __restrict__ kk_, u16* __restrict__ vt) {
  __shared__ union {
    u16 ab[2][2][128][32];  // [buf][A=0/B=1][row][col] linear, XOR-granule swizzled
    u16 tile[128][136];     // epilogue staging
  } sm;
  const int tid = threadIdx.x;
  const int wv = tid >> 6, lane = tid & 63;
  const int wm = wv >> 1, wn = wv & 1;
  const int lr = lane & 15, quad = lane >> 4;
  const int r0 = blockIdx.x * 128;
  const int j0 = blockIdx.y * 128;

  // DMA staging: wave wv covers rows e*64 + wv*16 .. +16 of both 128x32 tiles (one g2l16
  // each). Lane l writes LDS granule (row = base + l>>2, g = l&3); source granule must be
  // g ^ (row&3) = (l&3) ^ ((l>>2)&3).
  const int srow = lane >> 2;
  const int sg = ((lane & 3) ^ (srow & 3)) * 8;
  const u16* pA[2];
  const u16* pB[2];
#pragma unroll
  for (int e = 0; e < 2; e++) {
    pA[e] = xt + (size_t)(r0 + e * 64 + wv * 16 + srow) * 256 + sg;
    pB[e] = w + (size_t)(j0 + e * 64 + wv * 16 + srow) * 256 + sg;
  }
  auto stage = [&](int buf, int k0) {
#pragma unroll
    for (int e = 0; e < 2; e++) {
      g2l16(pA[e] + k0, &sm.ab[buf][0][e * 64 + wv * 16][0]);
      g2l16(pB[e] + k0, &sm.ab[buf][1][e * 64 + wv * 16][0]);
    }
  };

  f32x4 acc[4][4] = {};
  stage(0, 0);
  __syncthreads();
  for (int ks = 0; ks < 8; ks++) {
    const int cur = ks & 1;
    if (ks < 7) stage(cur ^ 1, (ks + 1) * 32);  // async; drains at loop-end barrier
    bf16x8 a[4], b[4];
#pragma unroll
    for (int mt = 0; mt < 4; mt++)
      a[mt] = ldfrag(&sm.ab[cur][0][wm * 64 + mt * 16 + lr][(quad ^ (lr & 3)) * 8]);
#pragma unroll
    for (int nt = 0; nt < 4; nt++)
      b[nt] = ldfrag(&sm.ab[cur][1][wn * 64 + nt * 16 + lr][(quad ^ (lr & 3)) * 8]);
#pragma unroll
    for (int mt = 0; mt < 4; mt++)
#pragma unroll
      for (int nt = 0; nt < 4; nt++)
        acc[mt][nt] = __builtin_amdgcn_mfma_f32_16x16x32_bf16(a[mt], b[nt], acc[mt][nt], 0, 0, 0);
    __syncthreads();
  }

  float bj[4];
#pragma unroll
  for (int nt = 0; nt < 4; nt++) bj[nt] = bias[j0 + wn * 64 + nt * 16 + lr];
  __syncthreads();  // safety: union overwrite
  if (blockIdx.y < 4) {
    // q/k path: stage (acc+bias)*sc to LDS, then coalesced u16x8 stores
    const int part = blockIdx.y >> 1;  // 0=q, 1=k
    u16* outp = part ? kk_ : q;
    const float sc = part ? 1.0f : 0.18033688f;  // 0.125*log2(e), exp2-domain scores
#pragma unroll
    for (int nt = 0; nt < 4; nt++) {
      int lc = wn * 64 + nt * 16 + lr;
#pragma unroll
      for (int mt = 0; mt < 4; mt++)
#pragma unroll
        for (int rg = 0; rg < 4; rg++)
          sm.tile[wm * 64 + mt * 16 + quad * 4 + rg][lc] = f2bf((acc[mt][nt][rg] + bj[nt]) * sc);
    }
    __syncthreads();
    const int hb2 = (blockIdx.y & 1) * 2;  // head base within part
#pragma unroll
    for (int it = 0; it < 8; it++) {
      int seg = tid + it * 256;            // 2048 u16x8 segments
      int row = seg >> 4, cs = seg & 15;   // consecutive tids -> consecutive cols (coalesced)
      u16x8 o = *(const u16x8*)&sm.tile[row][cs * 8];
      int head = hb2 + (cs >> 3), d0 = (cs & 7) * 8;
      int rr = r0 + row, b_ = rr >> 12, s = rr & 4095;
      *(u16x8*)(outp + ((size_t)((b_ * 4 + head) * Ss + s) << 6) + d0) = o;
    }
  } else {
    // v path: acc tile -> LDS -> transposed+permuted vt write
    const int hb = (blockIdx.y - 4) * 2;  // head base (0 or 2)
#pragma unroll
    for (int nt = 0; nt < 4; nt++) {
      int lc = wn * 64 + nt * 16 + lr;
#pragma unroll
      for (int mt = 0; mt < 4; mt++)
#pragma unroll
        for (int rg = 0; rg < 4; rg++)
          sm.tile[wm * 64 + mt * 16 + quad * 4 + rg][lc] = f2bf(acc[mt][nt][rg] + bj[nt]);
    }
    __syncthreads();
    const int b2 = r0 >> 12, sbase = r0 & 4095;
#pragma unroll
    for (int it = 0; it < 8; it++) {
      int seg = tid + it * 256;        // 2048 u16x8 segments
      int sq = seg & 15, hd = seg >> 4;  // consecutive tids -> consecutive slots (coalesced)
      int c = sq >> 3, s8 = sq & 7;
      u16x8 o;
#pragma unroll
      for (int j = 0; j < 8; j++) {
        int slot = s8 * 8 + j;
        int sw = (((slot >> 5) & 1) << 5) | (((slot >> 2) & 1) << 4) |
                 (((slot >> 3) & 3) << 2) | (slot & 3);  // k_vt's w6 bijection
        o[j] = sm.tile[c * 64 + sw][hd];
      }
      int head = hb + (hd >> 6), d = hd & 63;
      *(u16x8*)(vt + ((size_t)((b2 * 4 + head) * 64 + d) << 12) + sbase + c * 64 + s8 * 8) = o;
    }
  }
}

// ---------------- kernel 2: flash attention, S^T form, exp2 no-max softmax ----------------
// r11 structure (71.9 us, best measured): kv-split nsplit=2, 512-thread blocks, 8 waves of
// 32-q, 128-row kv big-chunks (two 64-row sub-tiles per barrier span), 2 blocks/CU.
__global__ __launch_bounds__(512, 4) void k_attn(const u16* __restrict__ Q, const u16* __restrict__ K,
                                                 const u16* __restrict__ VT, u16* __restrict__ AO,
                                                 u16* __restrict__ AOP, float* __restrict__ lpart,
                                                 int nsplit) {
  __shared__ u16 Kl[2][2][64][64];
  __shared__ u16 Vl[2][2][64][64];
  const int tid = threadIdx.x;
  const int wv = tid >> 6, lane = tid & 63;
  const int lr = lane & 15, quad = lane >> 4;
  const int bh = blockIdx.y;
  const int b_ = bh >> 2, head = bh & 3;
  const int qbase = blockIdx.x * 256 + wv * 32;
  const int sp = blockIdx.z;
  const int nbig = 32 / nsplit, bg0 = sp * nbig;  // big chunks of 128 kv rows
  const u16* Qh = Q + (size_t)bh * Ss * HD;
  const u16* Kh = K + (size_t)bh * Ss * HD;
  const u16* Vh = VT + (size_t)bh * HD * Ss;  // [d][perm(s)]

  bf16x8 qb[2][2];
#pragma unroll
  for (int nt = 0; nt < 2; nt++)
#pragma unroll
    for (int ks = 0; ks < 2; ks++)
      qb[nt][ks] = ldfrag(Qh + (size_t)(qbase + nt * 16 + lr) * HD + ks * 32 + quad * 8);

  u16x8 ov;
#pragma unroll
  for (int j = 0; j < 8; j++) ov[j] = 0x3F80;
  const bf16x8 ones = __builtin_bit_cast(bf16x8, ov);

  f32x4 O[2][4] = {};
  f32x4 lacc[2] = {};

  // DMA staging: per sub-tile, 8 waves cover 64 rows (wave wv: rows wv*8..wv*8+7). Lane l
  // writes LDS granule (row = wv*8 + l>>3, slot = l&7); source granule = (l&7)^(l>>3).
  const int srow = wv * 8 + (lane >> 3);
  const int sseg = ((lane & 7) ^ (lane >> 3)) * 8;
  const u16* pK = Kh + ((size_t)(bg0 * 128 + srow) << 6) + sseg;
  const u16* pV = Vh + ((size_t)srow << 12) + bg0 * 128 + sseg;
  auto stage = [&](int buf) {
#pragma unroll
    for (int s = 0; s < 2; s++) {
      g2l16(pK + (s << 12), &Kl[buf][s][wv * 8][0]);  // sub s: +64 rows * 64 cols
      g2l16(pV + s * 64, &Vl[buf][s][wv * 8][0]);     // sub s: +64 slots
    }
    pK += 8192; pV += 128;  // next big chunk (128 kv rows / 128 slots)
  };

  stage(0);
  __syncthreads();

  for (int bc = 0; bc < nbig; bc++) {
    const int cur = bc & 1;
    if (bc + 1 < nbig) stage(cur ^ 1);  // async into other buffer; drains at loop-end barrier

#pragma unroll
    for (int sub = 0; sub < 2; sub++) {
      u32x4 pa[2][2];  // [kv-half][q-group]: packed bf16 P fragments (PV A-operands)
#pragma unroll
      for (int t = 0; t < 4; t++) {  // 16-row kv tiles within sub
        const int krow = t * 16 + lr;
        bf16x8 ka0 = ldfrag(&Kl[cur][sub][krow][(quad ^ (lr & 7)) * 8]);
        bf16x8 ka1 = ldfrag(&Kl[cur][sub][krow][((4 + quad) ^ (lr & 7)) * 8]);
        f32x4 St[2] = {};
        __builtin_amdgcn_s_setprio(1);
#pragma unroll
        for (int nt = 0; nt < 2; nt++)
          St[nt] = __builtin_amdgcn_mfma_f32_16x16x32_bf16(ka0, qb[nt][0], St[nt], 0, 0, 0);
#pragma unroll
        for (int nt = 0; nt < 2; nt++)
          St[nt] = __builtin_amdgcn_mfma_f32_16x16x32_bf16(ka1, qb[nt][1], St[nt], 0, 0, 0);
        __builtin_amdgcn_s_setprio(0);
        const int h = t >> 1, k2 = (t & 1) * 2;
#pragma unroll
        for (int nt = 0; nt < 2; nt++) {
          float p0 = __builtin_amdgcn_exp2f(St[nt][0]);
          float p1 = __builtin_amdgcn_exp2f(St[nt][1]);
          float p2 = __builtin_amdgcn_exp2f(St[nt][2]);
          float p3 = __builtin_amdgcn_exp2f(St[nt][3]);
          pa[h][nt][k2] = pack2bf_trunc(p0, p1);
          pa[h][nt][k2 + 1] = pack2bf_trunc(p2, p3);
        }
      }
#pragma unroll
      for (int h = 0; h < 2; h++) {
#pragma unroll
        for (int dt = 0; dt < 4; dt++) {
          bf16x8 vb = ldfrag(&Vl[cur][sub][dt * 16 + lr][((h * 4 + quad) ^ (lr & 7)) * 8]);
          __builtin_amdgcn_s_setprio(1);
#pragma unroll
          for (int mt = 0; mt < 2; mt++)
            O[mt][dt] = __builtin_amdgcn_mfma_f32_16x16x32_bf16(
                __builtin_bit_cast(bf16x8, pa[h][mt]), vb, O[mt][dt], 0, 0, 0);
          __builtin_amdgcn_s_setprio(0);
        }
#pragma unroll
        for (int mt = 0; mt < 2; mt++)
          lacc[mt] = __builtin_amdgcn_mfma_f32_16x16x32_bf16(
              __builtin_bit_cast(bf16x8, pa[h][mt]), ones, lacc[mt], 0, 0, 0);
      }
    }
    __syncthreads();
  }

  // epilogue: normalize by this split's l, write bf16 (AO if nsplit==1, else partial slot sp)
  u16* dst = (nsplit == 1) ? AO : (AOP + (size_t)sp * ELEMS);
  if (nsplit > 1 && lr == 0) {
    float* lp = lpart + (size_t)sp * (16 * Ss) + bh * Ss;
#pragma unroll
    for (int mt = 0; mt < 2; mt++)
#pragma unroll
      for (int rg = 0; rg < 4; rg++) lp[qbase + mt * 16 + quad * 4 + rg] = lacc[mt][rg];
  }
#pragma unroll
  for (int mt = 0; mt < 2; mt++)
#pragma unroll
    for (int rg = 0; rg < 4; rg++) {
      float inv = 1.0f / lacc[mt][rg];
      int s = qbase + mt * 16 + quad * 4 + rg;
#pragma unroll
      for (int dt = 0; dt < 4; dt++)
        dst[((size_t)(b_ * Ss + s) << 8) + head * 64 + dt * 16 + lr] = f2bf(O[mt][dt][rg] * inv);
    }
}

// ---------------- kernel 3 (fused combine + oproj): y^T = w_o * combine(aop)^T + b_o ----------------
// 128(m) x 64(n) tiles, grid (256,2) = 512 blocks = 2 blocks/CU, 2 waves/SIMD.
// A-tile (wo) staged via global_load_lds with the same pre-swizzled-source pattern as k_qkv;
// B path (l-weighted combine of normalized bf16 partials) unchanged.
__global__ __launch_bounds__(256) void k_oproj(const u16* __restrict__ wo, const u16* __restrict__ ao,
                                               const u16* __restrict__ AOP, const float* __restrict__ lpart,
                                               const float* __restrict__ bo, float* __restrict__ y, int nsplit) {
  __shared__ u16 As[128][32], Bs[64][40];
  const int tid = threadIdx.x;
  const int wv = tid >> 6, lane = tid & 63;
  const int wm = wv >> 1, wn = wv & 1;
  const int lr = lane & 15, quad = lane >> 4;
  const int n0 = blockIdx.x * 64;
  const int m0 = blockIdx.y * 128;
  const int srow = lane >> 2;
  const int sg = ((lane & 3) ^ (srow & 3)) * 8;
  const u16* pA[2];
#pragma unroll
  for (int e = 0; e < 2; e++)
    pA[e] = wo + (size_t)(m0 + e * 64 + wv * 16 + srow) * 256 + sg;
  f32x4 acc[4][2] = {};
  for (int k0 = 0; k0 < 256; k0 += 32) {
    __syncthreads();
#pragma unroll
    for (int e = 0; e < 2; e++) g2l16(pA[e] + k0, &As[e * 64 + wv * 16][0]);  // A via DMA
    {  // B: 64 n-rows x 32 c-cols, l-weighted combine of normalized bf16 partials
      int row = tid >> 2, seg = tid & 3;
      int bs = n0 + row, cc = k0 + seg * 8;
      u16x8 t;
      if (nsplit == 1) {
        t = *(const u16x8*)(ao + ((size_t)bs << 8) + cc);
      } else {
        int b = bs >> 12, s = bs & 4095, head = cc >> 6;
        int li = (b * 4 + head) * Ss + s;
        float accv[8] = {0.f, 0.f, 0.f, 0.f, 0.f, 0.f, 0.f, 0.f};
        float lsum = 0.f;
        for (int spl = 0; spl < nsplit; spl++) {
          float l = lpart[(size_t)spl * (16 * Ss) + li];
          u16x8 a = *(const u16x8*)(AOP + (size_t)spl * ELEMS + ((size_t)bs << 8) + cc);
          lsum += l;
#pragma unroll
          for (int i = 0; i < 8; i++) accv[i] += l * bf2f(a[i]);
        }
        float inv = 1.0f / lsum;
#pragma unroll
        for (int i = 0; i < 8; i++) t[i] = f2bf(accv[i] * inv);
      }
      *(u16x8*)&Bs[row][seg * 8] = t;
    }
    __syncthreads();  // drains the A DMA + B writes
    bf16x8 a[4], b[2];
#pragma unroll
    for (int mt = 0; mt < 4; mt++)
      a[mt] = ldfrag(&As[wm * 64 + mt * 16 + lr][(quad ^ (lr & 3)) * 8]);
#pragma unroll
    for (int nt = 0; nt < 2; nt++) b[nt] = ldfrag(&Bs[wn * 32 + nt * 16 + lr][quad * 8]);
#pragma unroll
    for (int mt = 0; mt < 4; mt++)
#pragma unroll
      for (int nt = 0; nt < 2; nt++)
        acc[mt][nt] = __builtin_amdgcn_mfma_f32_16x16x32_bf16(a[mt], b[nt], acc[mt][nt], 0, 0, 0);
  }
#pragma unroll
  for (int mt = 0; mt < 4; mt++)
#pragma unroll
    for (int rg = 0; rg < 4; rg++) {
      int c = m0 + wm * 64 + mt * 16 + quad * 4 + rg;
      float bc = bo[c];
#pragma unroll
      for (int nt = 0; nt < 2; nt++) {
        int col = n0 + wn * 32 + nt * 16 + lr;
        int b_ = col >> 12, s = col & 4095;
        y[((size_t)(b_ * Cc + c) << 12) + s] = acc[mt][nt][rg] + bc;
      }
    }
}

extern "C" void kernel_launch(void* const* d_in, const int* in_sizes, int n_in,
                              void* d_out, int out_size, void* d_ws, size_t ws_size,
                              hipStream_t stream) {
  const float* x = (const float*)d_in[0];
  const float* w_qkv = (const float*)d_in[1];
  const float* b_qkv = (const float*)d_in[2];
  const float* w_o = (const float*)d_in[3];
  const float* b_o = (const float*)d_in[4];
  float* y = (float*)d_out;
  u16* ws = (u16*)d_ws;
  u16* xt = ws;                        // [0, E) — dead after k_qkv; reused as ao (nsplit==1)
  u16* q = ws + (size_t)ELEMS;
  u16* k = ws + (size_t)2 * ELEMS;
  u16* vt = ws + (size_t)3 * ELEMS;
  u16* ao = xt;
  u16* wqb = ws + (size_t)4 * ELEMS;   // 196608
  u16* wob = wqb + 196608;             // 65536
  const size_t Wu16 = (size_t)4 * ELEMS + 262144;
  // need(n) bytes = bf16 ws incl. n partial slabs, + n*16*Ss f32 for lpart
  auto need = [&](int n) { return (Wu16 + (size_t)n * ELEMS) * 2 + (size_t)n * 16 * Ss * 4; };
  const int nsplit = (ws_size >= need(2)) ? 2 : 1;
  u16* aop = ws + Wu16;                // nsplit*ELEMS u16 normalized partials
  float* lpart = (float*)(aop + (size_t)nsplit * ELEMS);

  k_transpose<<<dim3(64, 4, 4), 256, 0, stream>>>(x, xt, w_qkv, w_o, wqb, wob);
  k_qkv<<<dim3(128, 6), 256, 0, stream>>>(xt, wqb, b_qkv, q, k, vt);
  k_attn<<<dim3(16, 16, nsplit), 512, 0, stream>>>(q, k, vt, ao, aop, lpart, nsplit);
  k_oproj<<<dim3(256, 2), 256, 0, stream>>>(wob, ao, aop, lpart, b_o, y, nsplit);
}

// Round 13
// 165.914 us; speedup vs baseline: 1.1543x; 1.0118x over previous
//
#include <hip/hip_runtime.h>
#include <stdint.h>

#define DI __device__ __forceinline__

typedef __attribute__((ext_vector_type(8))) __bf16 bf16x8;
typedef __attribute__((ext_vector_type(8))) unsigned short u16x8;
typedef __attribute__((ext_vector_type(4))) float f32x4;
typedef __attribute__((ext_vector_type(4))) uint32_t u32x4;
typedef unsigned short u16;

constexpr int Bb = 4, Cc = 256, Ss = 4096, HD = 64;
constexpr int ELEMS = Bb * Cc * Ss;  // 4194304

DI float bf2f(u16 h) { union { unsigned u; float f; } x; x.u = ((unsigned)h) << 16; return x.f; }
DI u16 f2bf(float f) {
  union { float f; unsigned u; } x; x.f = f;
  return (u16)((x.u + 0x7FFFu + ((x.u >> 16) & 1u)) >> 16);
}
DI uint32_t pack2bf_trunc(float a, float b) {  // low16=bf(a), high16=bf(b), truncating
  union { float f; uint32_t u; } xa, xb;
  xa.f = a; xb.f = b;
  return __builtin_amdgcn_perm(xb.u, xa.u, 0x07060302u);
}
DI bf16x8 ldfrag(const u16* p) { return __builtin_bit_cast(bf16x8, *(const u16x8*)p); }

// async global->LDS DMA, 16B per lane. LDS dest = wave-uniform base + lane*16 (linear);
// source address is per-lane (carries the swizzle).
DI void g2l16(const u16* g, u16* l) {
  __builtin_amdgcn_global_load_lds((const __attribute__((address_space(1))) uint32_t*)(const void*)g,
                                   (__attribute__((address_space(3))) uint32_t*)(void*)l, 16, 0, 0);
}

// ---------------- kernel 0: x (B,C,S) fp32 -> xt (B,S,C) bf16; + weight conversion fused ----------------
__global__ __launch_bounds__(256) void k_transpose(const float* __restrict__ x, u16* __restrict__ xt,
                                                   const float* __restrict__ wq, const float* __restrict__ wo,
                                                   u16* __restrict__ wqb, u16* __restrict__ wob) {
  __shared__ u16 T[64][72];
  const int st = blockIdx.x, ct = blockIdx.y, b = blockIdx.z;
  const int tid = threadIdx.x;
  // fused weight conversion: 1024 blocks x 256 threads == 262144 == 196608 + 65536
  {
    int flat = blockIdx.x + 64 * blockIdx.y + 256 * blockIdx.z;
    int widx = flat * 256 + tid;
    if (widx < 196608) wqb[widx] = f2bf(wq[widx]);
    else wob[widx - 196608] = f2bf(wo[widx - 196608]);
  }
#pragma unroll
  for (int e = 0; e < 2; e++) {
    int ss = tid + e * 256;
    int r = ss >> 3, seg = ss & 7;
    size_t base = ((size_t)(b * Cc + ct * 64 + r) << 12) + st * 64 + seg * 8;
    const float4* xv = (const float4*)(x + base);
    float4 v0 = xv[0], v1 = xv[1];
    u16x8 t;
    t[0] = f2bf(v0.x); t[1] = f2bf(v0.y); t[2] = f2bf(v0.z); t[3] = f2bf(v0.w);
    t[4] = f2bf(v1.x); t[5] = f2bf(v1.y); t[6] = f2bf(v1.z); t[7] = f2bf(v1.w);
    *(u16x8*)&T[r][(seg ^ ((r >> 3) & 7)) * 8] = t;
  }
  __syncthreads();
#pragma unroll
  for (int e = 0; e < 2; e++) {
    int ss = tid + e * 256;
    int sr = ss >> 3, cseg = ss & 7;
    u16x8 o;
#pragma unroll
    for (int j = 0; j < 8; j++) {
      int row = cseg * 8 + j;
      o[j] = T[row][(((sr >> 3) ^ cseg) * 8) + (sr & 7)];
    }
    *(u16x8*)(xt + ((size_t)(b * Ss + st * 64 + sr) << 8) + ct * 64 + cseg * 8) = o;
  }
}

// ---------------- kernel 1: qkv GEMM + fused output layouts ----------------
// q:[bh][s][64]*(0.125*log2e)  k:[bh][s][64]  v -> vt [bh][d][chunk*64+slot] directly.
// Staging: linear [128][32] LDS tiles, double-buffered, global_load_lds DMA with
// pre-swizzled source granule g^(row&3), ONE barrier per K-step, DMA overlapped with MFMA.
__global__ __launch_bounds__(256) void k_qkv(const u16* __restrict__ xt, const u16* __restrict__ w,
                                             const float* __restrict__ bias,
                                             u16* __restrict__ q, u16* __restrict__ kk_, u16* __restrict__ vt) {
  __shared__ union {
    u16 ab[2][2][128][32];  // [buf][A=0/B=1][row][col] linear, XOR-granule swizzled
    u16 tile[128][136];     // epilogue staging
  } sm;
  const int tid = threadIdx.x;
  const int wv = tid >> 6, lane = tid & 63;
  const int wm = wv >> 1, wn = wv & 1;
  const int lr = lane & 15, quad = lane >> 4;
  const int r0 = blockIdx.x * 128;
  const int j0 = blockIdx.y * 128;

  // DMA staging: wave wv covers rows e*64 + wv*16 .. +16 of both 128x32 tiles. Lane l writes
  // LDS granule (row = base + l>>2, g = l&3); source granule = g ^ (row&3) = (l&3)^((l>>2)&3).
  const int srow = lane >> 2;
  const int sg = ((lane & 3) ^ (srow & 3)) * 8;
  const u16* pA[2];
  const u16* pB[2];
#pragma unroll
  for (int e = 0; e < 2; e++) {
    pA[e] = xt + (size_t)(r0 + e * 64 + wv * 16 + srow) * 256 + sg;
    pB[e] = w + (size_t)(j0 + e * 64 + wv * 16 + srow) * 256 + sg;
  }
  auto stage = [&](int buf, int k0) {
#pragma unroll
    for (int e = 0; e < 2; e++) {
      g2l16(pA[e] + k0, &sm.ab[buf][0][e * 64 + wv * 16][0]);
      g2l16(pB[e] + k0, &sm.ab[buf][1][e * 64 + wv * 16][0]);
    }
  };

  f32x4 acc[4][4] = {};
  stage(0, 0);
  __syncthreads();
  for (int ks = 0; ks < 8; ks++) {
    const int cur = ks & 1;
    if (ks < 7) stage(cur ^ 1, (ks + 1) * 32);  // async; drains at loop-end barrier
    bf16x8 a[4], b[4];
#pragma unroll
    for (int mt = 0; mt < 4; mt++)
      a[mt] = ldfrag(&sm.ab[cur][0][wm * 64 + mt * 16 + lr][(quad ^ (lr & 3)) * 8]);
#pragma unroll
    for (int nt = 0; nt < 4; nt++)
      b[nt] = ldfrag(&sm.ab[cur][1][wn * 64 + nt * 16 + lr][(quad ^ (lr & 3)) * 8]);
#pragma unroll
    for (int mt = 0; mt < 4; mt++)
#pragma unroll
      for (int nt = 0; nt < 4; nt++)
        acc[mt][nt] = __builtin_amdgcn_mfma_f32_16x16x32_bf16(a[mt], b[nt], acc[mt][nt], 0, 0, 0);
    __syncthreads();
  }

  float bj[4];
#pragma unroll
  for (int nt = 0; nt < 4; nt++) bj[nt] = bias[j0 + wn * 64 + nt * 16 + lr];
  __syncthreads();  // safety: union overwrite
  if (blockIdx.y < 4) {
    // q/k path: stage (acc+bias)*sc to LDS, then coalesced u16x8 stores
    const int part = blockIdx.y >> 1;  // 0=q, 1=k
    u16* outp = part ? kk_ : q;
    const float sc = part ? 1.0f : 0.18033688f;  // 0.125*log2(e), exp2-domain scores
#pragma unroll
    for (int nt = 0; nt < 4; nt++) {
      int lc = wn * 64 + nt * 16 + lr;
#pragma unroll
      for (int mt = 0; mt < 4; mt++)
#pragma unroll
        for (int rg = 0; rg < 4; rg++)
          sm.tile[wm * 64 + mt * 16 + quad * 4 + rg][lc] = f2bf((acc[mt][nt][rg] + bj[nt]) * sc);
    }
    __syncthreads();
    const int hb2 = (blockIdx.y & 1) * 2;  // head base within part
#pragma unroll
    for (int it = 0; it < 8; it++) {
      int seg = tid + it * 256;            // 2048 u16x8 segments
      int row = seg >> 4, cs = seg & 15;   // consecutive tids -> consecutive cols (coalesced)
      u16x8 o = *(const u16x8*)&sm.tile[row][cs * 8];
      int head = hb2 + (cs >> 3), d0 = (cs & 7) * 8;
      int rr = r0 + row, b_ = rr >> 12, s = rr & 4095;
      *(u16x8*)(outp + ((size_t)((b_ * 4 + head) * Ss + s) << 6) + d0) = o;
    }
  } else {
    // v path: acc tile -> LDS -> transposed+permuted vt write
    const int hb = (blockIdx.y - 4) * 2;  // head base (0 or 2)
#pragma unroll
    for (int nt = 0; nt < 4; nt++) {
      int lc = wn * 64 + nt * 16 + lr;
#pragma unroll
      for (int mt = 0; mt < 4; mt++)
#pragma unroll
        for (int rg = 0; rg < 4; rg++)
          sm.tile[wm * 64 + mt * 16 + quad * 4 + rg][lc] = f2bf(acc[mt][nt][rg] + bj[nt]);
    }
    __syncthreads();
    const int b2 = r0 >> 12, sbase = r0 & 4095;
#pragma unroll
    for (int it = 0; it < 8; it++) {
      int seg = tid + it * 256;        // 2048 u16x8 segments
      int sq = seg & 15, hd = seg >> 4;  // consecutive tids -> consecutive slots (coalesced)
      int c = sq >> 3, s8 = sq & 7;
      u16x8 o;
#pragma unroll
      for (int j = 0; j < 8; j++) {
        int slot = s8 * 8 + j;
        int sw = (((slot >> 5) & 1) << 5) | (((slot >> 2) & 1) << 4) |
                 (((slot >> 3) & 3) << 2) | (slot & 3);  // k_vt's w6 bijection
        o[j] = sm.tile[c * 64 + sw][hd];
      }
      int head = hb + (hd >> 6), d = hd & 63;
      *(u16x8*)(vt + ((size_t)((b2 * 4 + head) * 64 + d) << 12) + sbase + c * 64 + s8 * 8) = o;
    }
  }
}

// ---------------- kernel 2: flash attention, S^T form, exp2 no-max softmax ----------------
// r12 structure (70.0 us): kv-split nsplit=2, 512-thread blocks, 8 waves of 32-q, 128-row
// kv big-chunks, 2 blocks/CU. NEW: epilogue stages O rows in LDS (Kl/Vl dead after the loop,
// via union) so AO/AOP writes are 128B-contiguous u16x8 per 8-lane group (direct path was
// scattered 32B segments x 4 s-rows per wave-instr).
__global__ __launch_bounds__(512, 4) void k_attn(const u16* __restrict__ Q, const u16* __restrict__ K,
                                                 const u16* __restrict__ VT, u16* __restrict__ AO,
                                                 u16* __restrict__ AOP, float* __restrict__ lpart,
                                                 int nsplit) {
  __shared__ union {
    struct { u16 Kl[2][2][64][64]; u16 Vl[2][2][64][64]; } s;  // 64 KB
    u16 W[8][32 * 72];                                         // epilogue: per-wave [32 q][72]
  } smem;
  const int tid = threadIdx.x;
  const int wv = tid >> 6, lane = tid & 63;
  const int lr = lane & 15, quad = lane >> 4;
  const int bh = blockIdx.y;
  const int b_ = bh >> 2, head = bh & 3;
  const int qbase = blockIdx.x * 256 + wv * 32;
  const int sp = blockIdx.z;
  const int nbig = 32 / nsplit, bg0 = sp * nbig;  // big chunks of 128 kv rows
  const u16* Qh = Q + (size_t)bh * Ss * HD;
  const u16* Kh = K + (size_t)bh * Ss * HD;
  const u16* Vh = VT + (size_t)bh * HD * Ss;  // [d][perm(s)]

  bf16x8 qb[2][2];
#pragma unroll
  for (int nt = 0; nt < 2; nt++)
#pragma unroll
    for (int ks = 0; ks < 2; ks++)
      qb[nt][ks] = ldfrag(Qh + (size_t)(qbase + nt * 16 + lr) * HD + ks * 32 + quad * 8);

  u16x8 ov;
#pragma unroll
  for (int j = 0; j < 8; j++) ov[j] = 0x3F80;
  const bf16x8 ones = __builtin_bit_cast(bf16x8, ov);

  f32x4 O[2][4] = {};
  f32x4 lacc[2] = {};

  // DMA staging: per sub-tile, 8 waves cover 64 rows (wave wv: rows wv*8..wv*8+7). Lane l
  // writes LDS granule (row = wv*8 + l>>3, slot = l&7); source granule = (l&7)^(l>>3).
  const int srow = wv * 8 + (lane >> 3);
  const int sseg = ((lane & 7) ^ (lane >> 3)) * 8;
  const u16* pK = Kh + ((size_t)(bg0 * 128 + srow) << 6) + sseg;
  const u16* pV = Vh + ((size_t)srow << 12) + bg0 * 128 + sseg;
  auto stage = [&](int buf) {
#pragma unroll
    for (int s = 0; s < 2; s++) {
      g2l16(pK + (s << 12), &smem.s.Kl[buf][s][wv * 8][0]);  // sub s: +64 rows * 64 cols
      g2l16(pV + s * 64, &smem.s.Vl[buf][s][wv * 8][0]);     // sub s: +64 slots
    }
    pK += 8192; pV += 128;  // next big chunk (128 kv rows / 128 slots)
  };

  stage(0);
  __syncthreads();

  for (int bc = 0; bc < nbig; bc++) {
    const int cur = bc & 1;
    if (bc + 1 < nbig) stage(cur ^ 1);  // async into other buffer; drains at loop-end barrier

#pragma unroll
    for (int sub = 0; sub < 2; sub++) {
      u32x4 pa[2][2];  // [kv-half][q-group]: packed bf16 P fragments (PV A-operands)
#pragma unroll
      for (int t = 0; t < 4; t++) {  // 16-row kv tiles within sub
        const int krow = t * 16 + lr;
        bf16x8 ka0 = ldfrag(&smem.s.Kl[cur][sub][krow][(quad ^ (lr & 7)) * 8]);
        bf16x8 ka1 = ldfrag(&smem.s.Kl[cur][sub][krow][((4 + quad) ^ (lr & 7)) * 8]);
        f32x4 St[2] = {};
        __builtin_amdgcn_s_setprio(1);
#pragma unroll
        for (int nt = 0; nt < 2; nt++)
          St[nt] = __builtin_amdgcn_mfma_f32_16x16x32_bf16(ka0, qb[nt][0], St[nt], 0, 0, 0);
#pragma unroll
        for (int nt = 0; nt < 2; nt++)
          St[nt] = __builtin_amdgcn_mfma_f32_16x16x32_bf16(ka1, qb[nt][1], St[nt], 0, 0, 0);
        __builtin_amdgcn_s_setprio(0);
        const int h = t >> 1, k2 = (t & 1) * 2;
#pragma unroll
        for (int nt = 0; nt < 2; nt++) {
          float p0 = __builtin_amdgcn_exp2f(St[nt][0]);
          float p1 = __builtin_amdgcn_exp2f(St[nt][1]);
          float p2 = __builtin_amdgcn_exp2f(St[nt][2]);
          float p3 = __builtin_amdgcn_exp2f(St[nt][3]);
          pa[h][nt][k2] = pack2bf_trunc(p0, p1);
          pa[h][nt][k2 + 1] = pack2bf_trunc(p2, p3);
        }
      }
#pragma unroll
      for (int h = 0; h < 2; h++) {
#pragma unroll
        for (int dt = 0; dt < 4; dt++) {
          bf16x8 vb = ldfrag(&smem.s.Vl[cur][sub][dt * 16 + lr][((h * 4 + quad) ^ (lr & 7)) * 8]);
          __builtin_amdgcn_s_setprio(1);
#pragma unroll
          for (int mt = 0; mt < 2; mt++)
            O[mt][dt] = __builtin_amdgcn_mfma_f32_16x16x32_bf16(
                __builtin_bit_cast(bf16x8, pa[h][mt]), vb, O[mt][dt], 0, 0, 0);
          __builtin_amdgcn_s_setprio(0);
        }
#pragma unroll
        for (int mt = 0; mt < 2; mt++)
          lacc[mt] = __builtin_amdgcn_mfma_f32_16x16x32_bf16(
              __builtin_bit_cast(bf16x8, pa[h][mt]), ones, lacc[mt], 0, 0, 0);
      }
    }
    __syncthreads();
  }

  // epilogue: normalize by this split's l; stage rows in per-wave LDS tile (Kl/Vl are dead
  // after the final barrier), then 128B-contiguous u16x8 global writes.
  u16* dst = (nsplit == 1) ? AO : (AOP + (size_t)sp * ELEMS);
  if (nsplit > 1 && lr == 0) {
    float* lp = lpart + (size_t)sp * (16 * Ss) + bh * Ss;
#pragma unroll
    for (int mt = 0; mt < 2; mt++)
#pragma unroll
      for (int rg = 0; rg < 4; rg++) lp[qbase + mt * 16 + quad * 4 + rg] = lacc[mt][rg];
  }
  u16* W = smem.W[wv];
#pragma unroll
  for (int mt = 0; mt < 2; mt++)
#pragma unroll
    for (int rg = 0; rg < 4; rg++) {
      float inv = 1.0f / lacc[mt][rg];
      int qq = mt * 16 + quad * 4 + rg;
#pragma unroll
      for (int dt = 0; dt < 4; dt++)
        W[qq * 72 + dt * 16 + lr] = f2bf(O[mt][dt][rg] * inv);
    }
  // each wave reads only its own W region; ds-op ordering within the wave is sufficient
#pragma unroll
  for (int e = 0; e < 4; e++) {
    int seg = lane + e * 64;
    int qq = seg >> 3, d0 = (seg & 7) * 8;
    u16x8 o = *(const u16x8*)&W[qq * 72 + d0];
    *(u16x8*)(dst + ((size_t)(b_ * Ss + qbase + qq) << 8) + head * 64 + d0) = o;
  }
}

// ---------------- kernel 3 (fused combine + oproj): y^T = w_o * combine(aop)^T + b_o ----------------
// 128(m) x 64(n) tiles, grid (256,2) = 512 blocks = 2 blocks/CU, 2 waves/SIMD. A via DMA.
// NEW: epilogue stages the fp32 output tile in LDS (union over As/Bs) so y writes are
// 256B-contiguous float4 rows (direct path was 64B segments x 4 c-rows per wave-instr).
__global__ __launch_bounds__(256) void k_oproj(const u16* __restrict__ wo, const u16* __restrict__ ao,
                                               const u16* __restrict__ AOP, const float* __restrict__ lpart,
                                               const float* __restrict__ bo, float* __restrict__ y, int nsplit) {
  __shared__ union {
    struct { u16 As[128][32]; u16 Bs[64][40]; } s;
    float Ys[128][68];  // epilogue: 128 c x 64 s (pitch 68: 16B-aligned rows, 2-way banks)
  } sm;
  const int tid = threadIdx.x;
  const int wv = tid >> 6, lane = tid & 63;
  const int wm = wv >> 1, wn = wv & 1;
  const int lr = lane & 15, quad = lane >> 4;
  const int n0 = blockIdx.x * 64;
  const int m0 = blockIdx.y * 128;
  const int srow = lane >> 2;
  const int sg = ((lane & 3) ^ (srow & 3)) * 8;
  const u16* pA[2];
#pragma unroll
  for (int e = 0; e < 2; e++)
    pA[e] = wo + (size_t)(m0 + e * 64 + wv * 16 + srow) * 256 + sg;
  f32x4 acc[4][2] = {};
  for (int k0 = 0; k0 < 256; k0 += 32) {
    __syncthreads();
#pragma unroll
    for (int e = 0; e < 2; e++) g2l16(pA[e] + k0, &sm.s.As[e * 64 + wv * 16][0]);  // A via DMA
    {  // B: 64 n-rows x 32 c-cols, l-weighted combine of normalized bf16 partials
      int row = tid >> 2, seg = tid & 3;
      int bs = n0 + row, cc = k0 + seg * 8;
      u16x8 t;
      if (nsplit == 1) {
        t = *(const u16x8*)(ao + ((size_t)bs << 8) + cc);
      } else {
        int b = bs >> 12, s = bs & 4095, head = cc >> 6;
        int li = (b * 4 + head) * Ss + s;
        float accv[8] = {0.f, 0.f, 0.f, 0.f, 0.f, 0.f, 0.f, 0.f};
        float lsum = 0.f;
        for (int spl = 0; spl < nsplit; spl++) {
          float l = lpart[(size_t)spl * (16 * Ss) + li];
          u16x8 a = *(const u16x8*)(AOP + (size_t)spl * ELEMS + ((size_t)bs << 8) + cc);
          lsum += l;
#pragma unroll
          for (int i = 0; i < 8; i++) accv[i] += l * bf2f(a[i]);
        }
        float inv = 1.0f / lsum;
#pragma unroll
        for (int i = 0; i < 8; i++) t[i] = f2bf(accv[i] * inv);
      }
      *(u16x8*)&sm.s.Bs[row][seg * 8] = t;
    }
    __syncthreads();  // drains the A DMA + B writes
    bf16x8 a[4], b[2];
#pragma unroll
    for (int mt = 0; mt < 4; mt++)
      a[mt] = ldfrag(&sm.s.As[wm * 64 + mt * 16 + lr][(quad ^ (lr & 3)) * 8]);
#pragma unroll
    for (int nt = 0; nt < 2; nt++) b[nt] = ldfrag(&sm.s.Bs[wn * 32 + nt * 16 + lr][quad * 8]);
#pragma unroll
    for (int mt = 0; mt < 4; mt++)
#pragma unroll
      for (int nt = 0; nt < 2; nt++)
        acc[mt][nt] = __builtin_amdgcn_mfma_f32_16x16x32_bf16(a[mt], b[nt], acc[mt][nt], 0, 0, 0);
  }
  __syncthreads();  // done with As/Bs (union overwrite)
#pragma unroll
  for (int mt = 0; mt < 4; mt++)
#pragma unroll
    for (int rg = 0; rg < 4; rg++) {
      int c = wm * 64 + mt * 16 + quad * 4 + rg;  // local c row
      float bc = bo[m0 + c];
#pragma unroll
      for (int nt = 0; nt < 2; nt++)
        sm.Ys[c][wn * 32 + nt * 16 + lr] = acc[mt][nt][rg] + bc;
    }
  __syncthreads();
  const int bglob = n0 >> 12, scol = n0 & 4095;
#pragma unroll
  for (int it = 0; it < 8; it++) {
    int idx = tid + it * 256;            // 2048 float4 segments
    int row = idx >> 4, s4 = (idx & 15) * 4;  // consecutive tids -> consecutive cols
    float4 v = *(const float4*)&sm.Ys[row][s4];
    *(float4*)&y[((size_t)(bglob * Cc + m0 + row) << 12) + scol + s4] = v;
  }
}

extern "C" void kernel_launch(void* const* d_in, const int* in_sizes, int n_in,
                              void* d_out, int out_size, void* d_ws, size_t ws_size,
                              hipStream_t stream) {
  const float* x = (const float*)d_in[0];
  const float* w_qkv = (const float*)d_in[1];
  const float* b_qkv = (const float*)d_in[2];
  const float* w_o = (const float*)d_in[3];
  const float* b_o = (const float*)d_in[4];
  float* y = (float*)d_out;
  u16* ws = (u16*)d_ws;
  u16* xt = ws;                        // [0, E) — dead after k_qkv; reused as ao (nsplit==1)
  u16* q = ws + (size_t)ELEMS;
  u16* k = ws + (size_t)2 * ELEMS;
  u16* vt = ws + (size_t)3 * ELEMS;
  u16* ao = xt;
  u16* wqb = ws + (size_t)4 * ELEMS;   // 196608
  u16* wob = wqb + 196608;             // 65536
  const size_t Wu16 = (size_t)4 * ELEMS + 262144;
  // need(n) bytes = bf16 ws incl. n partial slabs, + n*16*Ss f32 for lpart
  auto need = [&](int n) { return (Wu16 + (size_t)n * ELEMS) * 2 + (size_t)n * 16 * Ss * 4; };
  const int nsplit = (ws_size >= need(2)) ? 2 : 1;
  u16* aop = ws + Wu16;                // nsplit*ELEMS u16 normalized partials
  float* lpart = (float*)(aop + (size_t)nsplit * ELEMS);

  k_transpose<<<dim3(64, 4, 4), 256, 0, stream>>>(x, xt, w_qkv, w_o, wqb, wob);
  k_qkv<<<dim3(128, 6), 256, 0, stream>>>(xt, wqb, b_qkv, q, k, vt);
  k_attn<<<dim3(16, 16, nsplit), 512, 0, stream>>>(q, k, vt, ao, aop, lpart, nsplit);
  k_oproj<<<dim3(256, 2), 256, 0, stream>>>(wob, ao, aop, lpart, b_o, y, nsplit);
}